// Round 10
// baseline (320.662 us; speedup 1.0000x reference)
//
#include <hip/hip_runtime.h>
#include <stdint.h>

#define H 128
#define TM 16
#define MAXDEG 24        // tier B layout
#define BSTR16 16        // tier A bucket row: [count, e0..e14] = 16 ints = one 64B line
#define OVFCAP 4096      // tier A overflow side-array capacity (deg>15 spill)

typedef __attribute__((ext_vector_type(8))) short short8;
typedef __attribute__((ext_vector_type(4))) float f32x4;
typedef __attribute__((ext_vector_type(4))) int i32x4;

__device__ __forceinline__ unsigned short f2bf(float f) {
    union { float f; unsigned u; } v; v.f = f;
    unsigned u = v.u;
    u += 0x7fffu + ((u >> 16) & 1u);   // round-to-nearest-even
    return (unsigned short)(u >> 16);
}

__device__ __forceinline__ float bf2f(unsigned short u) {
    union { unsigned u; float f; } v; v.u = ((unsigned)u) << 16; return v.f;
}

__device__ __forceinline__ short8 cvt8(f32x4 a, f32x4 b) {
    short8 r;
    r[0] = (short)f2bf(a.x); r[1] = (short)f2bf(a.y);
    r[2] = (short)f2bf(a.z); r[3] = (short)f2bf(a.w);
    r[4] = (short)f2bf(b.x); r[5] = (short)f2bf(b.y);
    r[6] = (short)f2bf(b.z); r[7] = (short)f2bf(b.w);
    return r;
}

__device__ __forceinline__ void gadd(int entry, const unsigned short* xb,
                                     const short* emb_s, int l, float* acc) {
    int s = entry & 0x3FFFF, t = entry >> 18;
    short8 xv = *(const short8*)(xb + (size_t)s * H + l * 8);
    short8 ev = *(const short8*)&emb_s[t * 136 + l * 8];
#pragma unroll
    for (int j = 0; j < 8; ++j)
        acc[j] += bf2f((unsigned short)xv[j]) + bf2f((unsigned short)ev[j]);
}

__device__ __forceinline__ void csr_insert(int src, int dst, int t,
                                           int* bucket, int* ovf) {
    int entry = src | (t << 18);
    int* row = bucket + ((size_t)dst << 4);
    int pos = atomicAdd(row, 1);
    if (pos < 15) {
        row[1 + pos] = entry;
    } else {
        int j = atomicAdd(ovf, 1);
        if (j < OVFCAP) { ovf[8 + 2 * j] = dst; ovf[8 + 2 * j + 1] = entry; }
    }
}

// ---------------------------------------------------------------------------
// Tier A prep: one conversion unit per thread (full occupancy) + edges sliced
// UNIFORMLY across all blocks (~47 edges/block at this shape) so every
// block's ~2 atomic chains overlap its 256 conversion threads, instead of
// concentrating all 600K atomics in the first 18% of blocks (R8 lesson).
// NT loads AND NT stores on the conversion stream keep L2 free for bucket
// lines (conversion data is write-once/read-much-later; bucket is hot RMW).
// Bucket row = 16 ints (one 64B line): row[0]=count, row[1+pos]=entry.
// ---------------------------------------------------------------------------
__global__ __launch_bounds__(256) void prep_kernel(
    const float* __restrict__ x, const float* __restrict__ emb,
    unsigned short* __restrict__ xb, unsigned short* __restrict__ embb,
    const int* __restrict__ ei, const int* __restrict__ et,
    int* __restrict__ bucket, int* __restrict__ ovf,
    int total8x, int total8e, int E)
{
    const int tid = threadIdx.x;
    const int i = blockIdx.x * 256 + tid;

    // ---- this block's edge slice (uniform across grid) ----
    const int nb = gridDim.x;
    const int e0 = (int)(((long long)blockIdx.x * E) / nb);
    const int e1 = (int)(((long long)(blockIdx.x + 1) * E) / nb);

    // ---- issue first-round edge loads early (overlap with conversion) ----
    int src = 0, dst = 0, t = 0;
    int e = e0 + tid;
    const bool hasE = (e < e1);
    if (hasE) {
        src = ei[e];
        dst = ei[E + e];
        t   = et[e];
    }

    // ---- streaming conversion (NT both ways: bypass L2) ----
    if (i < total8x) {
        f32x4 a = __builtin_nontemporal_load(((const f32x4*)x) + 2 * i);
        f32x4 b = __builtin_nontemporal_load(((const f32x4*)x) + 2 * i + 1);
        __builtin_nontemporal_store(cvt8(a, b), ((short8*)xb) + i);
    } else if (i < total8x + total8e) {
        int j = i - total8x;
        f32x4 a = __builtin_nontemporal_load(((const f32x4*)emb) + 2 * j);
        f32x4 b = __builtin_nontemporal_load(((const f32x4*)emb) + 2 * j + 1);
        __builtin_nontemporal_store(cvt8(a, b), ((short8*)embb) + j);
    }

    // ---- CSR insert (atomic latency hidden under the conversion above) ----
    if (hasE) csr_insert(src, dst, t, bucket, ovf);

    // rare tail: slice larger than one thread-round (not at default shapes)
    for (e = e0 + 256 + tid; e < e1; e += 256) {
        csr_insert(ei[e], ei[E + e], et[e], bucket, ovf);
    }
}

// Tier B prep: CSR only (old separate cnt/bucket layout).
__global__ __launch_bounds__(256) void prep_edges_kernel(
    const int* __restrict__ ei, const int* __restrict__ et,
    int* __restrict__ cnt, int* __restrict__ bucket, int E)
{
    int e = blockIdx.x * 256 + threadIdx.x;
    if (e >= E) return;
    int src = ei[e];
    int dst = ei[E + e];
    int t   = et[e];
    int pos = atomicAdd(&cnt[dst], 1);
    if (pos < MAXDEG) bucket[(size_t)dst * MAXDEG + pos] = src | (t << 18);
}

// ---------------------------------------------------------------------------
// Tier A aggregate: bf16 gather, fp32 accumulate, bf16 write. (R6-R8 proven)
// One 16-lane group per node. Header quad = count + entries 0..2.
// deg>15: 15 inline entries + ovf scan. Spill-overflow: full E-scan.
// ---------------------------------------------------------------------------
__global__ __launch_bounds__(256) void aggregate_bf16_kernel(
    const unsigned short* __restrict__ xb, const unsigned short* __restrict__ embb,
    const int* __restrict__ bucket, const int* __restrict__ ovf,
    const int* __restrict__ ei, const int* __restrict__ et,
    unsigned short* __restrict__ aggb, int N, int E, int T)
{
    __shared__ __align__(16) short emb_s[16 * 136];   // padded stride 136

    const int tid = threadIdx.x;
    const int l   = tid & 15;      // feature chunk: l*8 .. l*8+7
    if (tid < T * 16) {
        int t = tid >> 4;
        *(short8*)&emb_s[t * 136 + l * 8] = *(const short8*)(embb + t * H + l * 8);
    }
    __syncthreads();

    const int nGroups = N >> 4;
    for (int g = blockIdx.x; g < nGroups; g += gridDim.x) {
        const int node = (g << 4) + (tid >> 4);

        const int* row = bucket + ((size_t)node << 4);
        i32x4 q = *(const i32x4*)row;   // count + entries 0,1,2
        const int c = q.x;

        float acc[8] = {0.f, 0.f, 0.f, 0.f, 0.f, 0.f, 0.f, 0.f};

        bool fullscan = false;
        int cc = c, nov = 0;
        if (c > 15) {
            nov = ovf[0];
            if (nov > OVFCAP) fullscan = true;   // spill overflowed: rescan
            cc = 15;
        }

        if (!fullscan) {
            {
                const bool b0 = cc > 0, b1 = cc > 1, b2 = cc > 2;
                short8 xv0, xv1, xv2, ev0, ev1, ev2;
                if (b0) {
                    int s = q.y & 0x3FFFF, t = q.y >> 18;
                    xv0 = *(const short8*)(xb + (size_t)s * H + l * 8);
                    ev0 = *(const short8*)&emb_s[t * 136 + l * 8];
                }
                if (b1) {
                    int s = q.z & 0x3FFFF, t = q.z >> 18;
                    xv1 = *(const short8*)(xb + (size_t)s * H + l * 8);
                    ev1 = *(const short8*)&emb_s[t * 136 + l * 8];
                }
                if (b2) {
                    int s = q.w & 0x3FFFF, t = q.w >> 18;
                    xv2 = *(const short8*)(xb + (size_t)s * H + l * 8);
                    ev2 = *(const short8*)&emb_s[t * 136 + l * 8];
                }
                if (b0) {
#pragma unroll
                    for (int j = 0; j < 8; ++j) acc[j] += bf2f((unsigned short)xv0[j]) + bf2f((unsigned short)ev0[j]);
                }
                if (b1) {
#pragma unroll
                    for (int j = 0; j < 8; ++j) acc[j] += bf2f((unsigned short)xv1[j]) + bf2f((unsigned short)ev1[j]);
                }
                if (b2) {
#pragma unroll
                    for (int j = 0; j < 8; ++j) acc[j] += bf2f((unsigned short)xv2[j]) + bf2f((unsigned short)ev2[j]);
                }
            }
            for (int i0 = 3; i0 < cc; i0 += 4) {
                i32x4 p = *(const i32x4*)(row + 1 + i0);   // entries i0..i0+3
                const int rem = cc - i0;
                const bool h1 = rem > 1, h2 = rem > 2, h3 = rem > 3;
                short8 xv0, xv1, xv2, xv3, ev0, ev1, ev2, ev3;
                {
                    int s = p.x & 0x3FFFF, t = p.x >> 18;
                    xv0 = *(const short8*)(xb + (size_t)s * H + l * 8);
                    ev0 = *(const short8*)&emb_s[t * 136 + l * 8];
                }
                if (h1) {
                    int s = p.y & 0x3FFFF, t = p.y >> 18;
                    xv1 = *(const short8*)(xb + (size_t)s * H + l * 8);
                    ev1 = *(const short8*)&emb_s[t * 136 + l * 8];
                }
                if (h2) {
                    int s = p.z & 0x3FFFF, t = p.z >> 18;
                    xv2 = *(const short8*)(xb + (size_t)s * H + l * 8);
                    ev2 = *(const short8*)&emb_s[t * 136 + l * 8];
                }
                if (h3) {
                    int s = p.w & 0x3FFFF, t = p.w >> 18;
                    xv3 = *(const short8*)(xb + (size_t)s * H + l * 8);
                    ev3 = *(const short8*)&emb_s[t * 136 + l * 8];
                }
#pragma unroll
                for (int j = 0; j < 8; ++j) acc[j] += bf2f((unsigned short)xv0[j]) + bf2f((unsigned short)ev0[j]);
                if (h1) {
#pragma unroll
                    for (int j = 0; j < 8; ++j) acc[j] += bf2f((unsigned short)xv1[j]) + bf2f((unsigned short)ev1[j]);
                }
                if (h2) {
#pragma unroll
                    for (int j = 0; j < 8; ++j) acc[j] += bf2f((unsigned short)xv2[j]) + bf2f((unsigned short)ev2[j]);
                }
                if (h3) {
#pragma unroll
                    for (int j = 0; j < 8; ++j) acc[j] += bf2f((unsigned short)xv3[j]) + bf2f((unsigned short)ev3[j]);
                }
            }
            if (c > 15) {
                for (int j = 0; j < nov; ++j) {
                    if (ovf[8 + 2 * j] == node) gadd(ovf[8 + 2 * j + 1], xb, emb_s, l, acc);
                }
            }
        } else {
            for (int e = 0; e < E; ++e) {
                if (ei[E + e] == node) gadd(ei[e] | (et[e] << 18), xb, emb_s, l, acc);
            }
        }

        short8 r;
#pragma unroll
        for (int j = 0; j < 8; ++j) r[j] = (short)f2bf(acc[j]);
        *(short8*)(aggb + (size_t)node * H + l * 8) = r;
    }
}

// ---------------------------------------------------------------------------
// Tier A GEMM+LN: R5 structure (2 barriers, separate a/o buffers). Grid 1024
// = 4 blocks/CU (LDS cap), all resident; ~6 tiles/block amortizes the weight
// prologue. LN: line-complete NT stores. (R8-proven, ~55us)
// ---------------------------------------------------------------------------
__global__ __launch_bounds__(256) void gemm_ln32_kernel(
    const unsigned short* __restrict__ xb, const unsigned short* __restrict__ aggb,
    const float* __restrict__ Wself, const float* __restrict__ bself,
    const float* __restrict__ Wmsg, const float* __restrict__ bmsg,
    const float* __restrict__ gamma, const float* __restrict__ beta,
    float* __restrict__ out, int nSuper)
{
    __shared__ __align__(16) short a_stage[32 * 264];  // 32 x (256+8 pad) bf16
    __shared__ __align__(16) float o_stage[32 * 132];  // 32 x (128+4 pad) f32

    const int tid  = threadIdx.x;
    const int wave = tid >> 6;
    const int lane = tid & 63;
    const int col  = lane & 15;
    const int quad = lane >> 4;

    // ---- B fragments (weights, bf16) into registers; once per block ----
    short8 bfrag[2][8];
    float bias[2];
#pragma unroll
    for (int s = 0; s < 2; ++s) {
        const int h = (wave * 2 + s) * 16 + col;
        bias[s] = bself[h] + bmsg[h];
#pragma unroll
        for (int kst = 0; kst < 8; ++kst) {
            const float* W = (kst < 4) ? Wself : Wmsg;
            const int k0 = (kst & 3) * 32 + quad * 8;
            const float* p = W + (size_t)h * H + k0;
            bfrag[s][kst] = cvt8(*(const f32x4*)p, *(const f32x4*)(p + 4));
        }
    }

    // LN mapping: 16 lanes/row; lane l owns feats [l4,+4) and [64+l4,+4)
    const int lrow = tid >> 4;           // 0..15 (row within 16-row half)
    const int l4 = (tid & 15) * 4;
    f32x4 g0  = *(const f32x4*)(gamma + l4);
    f32x4 g1  = *(const f32x4*)(gamma + 64 + l4);
    f32x4 be0 = *(const f32x4*)(beta + l4);
    f32x4 be1 = *(const f32x4*)(beta + 64 + l4);

    const int srow = tid >> 3;   // 0..31: staging row
    const int sq   = tid & 7;    // 0..7

    for (int st = blockIdx.x; st < nSuper; st += gridDim.x) {
        const size_t rowBase = (size_t)st * 32;

        // ---- stage 32x256 bf16: sq<4 -> xb chunks, sq>=4 -> aggb chunks ----
        {
            const unsigned short* src = (sq < 4)
                ? (xb   + (rowBase + srow) * H + sq * 32)
                : (aggb + (rowBase + srow) * H + (sq - 4) * 32);
            short* dstl = &a_stage[srow * 264 + (sq & 3) * 32 + ((sq >> 2) << 7)];
            *(short8*)(dstl)      = ((const short8*)src)[0];
            *(short8*)(dstl + 8)  = ((const short8*)src)[1];
            *(short8*)(dstl + 16) = ((const short8*)src)[2];
            *(short8*)(dstl + 24) = ((const short8*)src)[3];
        }
        __syncthreads();   // sync#1: a_stage visible

        // ---- MFMA: 2 row-tiles x 2 feature-halves, K=256 ----
        f32x4 acc00 = {0.f,0.f,0.f,0.f}, acc01 = {0.f,0.f,0.f,0.f};
        f32x4 acc10 = {0.f,0.f,0.f,0.f}, acc11 = {0.f,0.f,0.f,0.f};
        {
            short8 afr[8];
#pragma unroll
            for (int kst = 0; kst < 8; ++kst)
                afr[kst] = *(const short8*)&a_stage[col * 264 + kst * 32 + quad * 8];
#pragma unroll
            for (int kst = 0; kst < 8; ++kst) {
                acc00 = __builtin_amdgcn_mfma_f32_16x16x32_bf16(afr[kst], bfrag[0][kst], acc00, 0, 0, 0);
                acc01 = __builtin_amdgcn_mfma_f32_16x16x32_bf16(afr[kst], bfrag[1][kst], acc01, 0, 0, 0);
            }
#pragma unroll
            for (int kst = 0; kst < 8; ++kst)
                afr[kst] = *(const short8*)&a_stage[(16 + col) * 264 + kst * 32 + quad * 8];
#pragma unroll
            for (int kst = 0; kst < 8; ++kst) {
                acc10 = __builtin_amdgcn_mfma_f32_16x16x32_bf16(afr[kst], bfrag[0][kst], acc10, 0, 0, 0);
                acc11 = __builtin_amdgcn_mfma_f32_16x16x32_bf16(afr[kst], bfrag[1][kst], acc11, 0, 0, 0);
            }
        }

        // ---- bias + relu -> o_stage ----
        {
            const int h0 = (wave * 2) * 16 + col;
            const int h1 = h0 + 16;
#pragma unroll
            for (int r = 0; r < 4; ++r) {
                const int m = quad * 4 + r;
                float v;
                v = acc00[r] + bias[0]; o_stage[m * 132 + h0]        = v > 0.f ? v : 0.f;
                v = acc01[r] + bias[1]; o_stage[m * 132 + h1]        = v > 0.f ? v : 0.f;
                v = acc10[r] + bias[0]; o_stage[(16 + m) * 132 + h0] = v > 0.f ? v : 0.f;
                v = acc11[r] + bias[1]; o_stage[(16 + m) * 132 + h1] = v > 0.f ? v : 0.f;
            }
        }
        __syncthreads();   // sync#2: o_stage visible; all a_stage reads retired

        // ---- LayerNorm: two 16-row passes; line-complete NT stores ----
#pragma unroll
        for (int half = 0; half < 2; ++half) {
            const int row = half * 16 + lrow;
            const float* orow = &o_stage[row * 132];
            f32x4 va = *(const f32x4*)(orow + l4);        // feats l4..l4+3
            f32x4 vb = *(const f32x4*)(orow + 64 + l4);   // feats 64+l4..

            float s1 = (va.x + va.y + va.z + va.w) + (vb.x + vb.y + vb.z + vb.w);
            float s2 = va.x*va.x + va.y*va.y + va.z*va.z + va.w*va.w
                     + vb.x*vb.x + vb.y*vb.y + vb.z*vb.z + vb.w*vb.w;
#pragma unroll
            for (int m = 1; m < 16; m <<= 1) {
                s1 += __shfl_xor(s1, m, 64);
                s2 += __shfl_xor(s2, m, 64);
            }
            const float mu = s1 * (1.f / 128.f);
            const float var = s2 * (1.f / 128.f) - mu * mu;
            const float rstd = rsqrtf(var + 1e-5f);

            f32x4 o0, o1;
            o0.x = (va.x - mu) * rstd * g0.x + be0.x;
            o0.y = (va.y - mu) * rstd * g0.y + be0.y;
            o0.z = (va.z - mu) * rstd * g0.z + be0.z;
            o0.w = (va.w - mu) * rstd * g0.w + be0.w;
            o1.x = (vb.x - mu) * rstd * g1.x + be1.x;
            o1.y = (vb.y - mu) * rstd * g1.y + be1.y;
            o1.z = (vb.z - mu) * rstd * g1.z + be1.z;
            o1.w = (vb.w - mu) * rstd * g1.w + be1.w;

            float* dst = out + (rowBase + row) * H;
            __builtin_nontemporal_store(o0, (f32x4*)(dst + l4));
            __builtin_nontemporal_store(o1, (f32x4*)(dst + 64 + l4));
        }
        // no trailing barrier: next-iter a_stage writes happen only after
        // every wave passed sync#2.
    }
}

// ---------------------------------------------------------------------------
// Tier B (round-1 proven): fp32 gather aggregate + 16-row gemm reading fp32 x.
// ---------------------------------------------------------------------------
__global__ __launch_bounds__(256) void aggregate_f32_kernel(
    const float* __restrict__ x, const float* __restrict__ emb,
    const int* __restrict__ cnt, const int* __restrict__ bucket,
    const int* __restrict__ ei, const int* __restrict__ et,
    unsigned short* __restrict__ aggb, int N, int E, int T)
{
    __shared__ __align__(16) float emb_s[16 * 132];

    const int tid = threadIdx.x;
    for (int i = tid; i < T * H; i += 256)
        emb_s[(i >> 7) * 132 + (i & 127)] = emb[i];
    __syncthreads();

    const int l = tid & 15;
    const int nGroups = N >> 4;

    for (int g = blockIdx.x; g < nGroups; g += gridDim.x) {
        const int node = (g << 4) + (tid >> 4);
        const int* b = bucket + (size_t)node * MAXDEG;
        i32x4 p = *(const i32x4*)b;
        const int c = cnt[node];

        f32x4 acc0 = {0.f,0.f,0.f,0.f};
        f32x4 acc1 = {0.f,0.f,0.f,0.f};

        if (c <= MAXDEG) {
            for (int i0 = 0; i0 < c; i0 += 4) {
                if (i0 > 0) p = *(const i32x4*)(b + i0);
                const int rem = c - i0;
                const bool h1 = rem > 1, h2 = rem > 2, h3 = rem > 3;
                f32x4 x00,x01,e00,e01,x10,x11,e10,e11,x20,x21,e20,e21,x30,x31,e30,e31;
                {
                    int s = p.x & 0x3FFFF, t = p.x >> 18;
                    const float* xp = x + (size_t)s * H + l * 8;
                    const float* ep = emb_s + t * 132 + l * 8;
                    x00 = *(const f32x4*)xp; x01 = *(const f32x4*)(xp + 4);
                    e00 = *(const f32x4*)ep; e01 = *(const f32x4*)(ep + 4);
                }
                if (h1) {
                    int s = p.y & 0x3FFFF, t = p.y >> 18;
                    const float* xp = x + (size_t)s * H + l * 8;
                    const float* ep = emb_s + t * 132 + l * 8;
                    x10 = *(const f32x4*)xp; x11 = *(const f32x4*)(xp + 4);
                    e10 = *(const f32x4*)ep; e11 = *(const f32x4*)(ep + 4);
                }
                if (h2) {
                    int s = p.z & 0x3FFFF, t = p.z >> 18;
                    const float* xp = x + (size_t)s * H + l * 8;
                    const float* ep = emb_s + t * 132 + l * 8;
                    x20 = *(const f32x4*)xp; x21 = *(const f32x4*)(xp + 4);
                    e20 = *(const f32x4*)ep; e21 = *(const f32x4*)(ep + 4);
                }
                if (h3) {
                    int s = p.w & 0x3FFFF, t = p.w >> 18;
                    const float* xp = x + (size_t)s * H + l * 8;
                    const float* ep = emb_s + t * 132 + l * 8;
                    x30 = *(const f32x4*)xp; x31 = *(const f32x4*)(xp + 4);
                    e30 = *(const f32x4*)ep; e31 = *(const f32x4*)(ep + 4);
                }
                acc0 += x00 + e00;  acc1 += x01 + e01;
                if (h1) { acc0 += x10 + e10;  acc1 += x11 + e11; }
                if (h2) { acc0 += x20 + e20;  acc1 += x21 + e21; }
                if (h3) { acc0 += x30 + e30;  acc1 += x31 + e31; }
            }
        } else {
            for (int e = 0; e < E; ++e) {
                if (ei[E + e] == node) {
                    int s = ei[e], t = et[e];
                    const float* xp = x + (size_t)s * H + l * 8;
                    const float* ep = emb_s + t * 132 + l * 8;
                    f32x4 a0 = *(const f32x4*)xp, a1 = *(const f32x4*)(xp + 4);
                    f32x4 b0 = *(const f32x4*)ep, b1 = *(const f32x4*)(ep + 4);
                    acc0 += a0 + b0;  acc1 += a1 + b1;
                }
            }
        }
        *(short8*)(aggb + (size_t)node * H + l * 8) = cvt8(acc0, acc1);
    }
}

__global__ __launch_bounds__(256) void gemm_ln16_kernel(
    const float* __restrict__ x, const unsigned short* __restrict__ aggb,
    const float* __restrict__ Wself, const float* __restrict__ bself,
    const float* __restrict__ Wmsg, const float* __restrict__ bmsg,
    const float* __restrict__ gamma, const float* __restrict__ beta,
    float* __restrict__ out, int nTiles)
{
    __shared__ __align__(16) short a_stage[TM * 264];
    __shared__ __align__(16) float o_stage[TM * 132];

    const int tid  = threadIdx.x;
    const int wave = tid >> 6;
    const int lane = tid & 63;
    const int col  = lane & 15;
    const int quad = lane >> 4;

    short8 bfrag[2][8];
    float bias[2];
#pragma unroll
    for (int s = 0; s < 2; ++s) {
        const int h = (wave * 2 + s) * 16 + col;
        bias[s] = bself[h] + bmsg[h];
#pragma unroll
        for (int kst = 0; kst < 8; ++kst) {
            const float* W = (kst < 4) ? Wself : Wmsg;
            const int k0 = (kst & 3) * 32 + quad * 8;
            const float* p = W + (size_t)h * H + k0;
            bfrag[s][kst] = cvt8(*(const f32x4*)p, *(const f32x4*)(p + 4));
        }
    }

    const int lnode = tid >> 4;
    const int f0 = (tid & 15) * 8;
    f32x4 g0  = *(const f32x4*)(gamma + f0);
    f32x4 g1  = *(const f32x4*)(gamma + f0 + 4);
    f32x4 be0 = *(const f32x4*)(beta + f0);
    f32x4 be1 = *(const f32x4*)(beta + f0 + 4);

    const int node = tid >> 4;
    const int seg  = tid & 15;

    for (int tile = blockIdx.x; tile < nTiles; tile += gridDim.x) {
        const size_t rowBase = (size_t)tile * TM;
        if (seg < 8) {
            const float* src = x + (rowBase + node) * H + seg * 16;
            f32x4 v0 = ((const f32x4*)src)[0];
            f32x4 v1 = ((const f32x4*)src)[1];
            f32x4 v2 = ((const f32x4*)src)[2];
            f32x4 v3 = ((const f32x4*)src)[3];
            *(short8*)&a_stage[node * 264 + seg * 16]     = cvt8(v0, v1);
            *(short8*)&a_stage[node * 264 + seg * 16 + 8] = cvt8(v2, v3);
        } else {
            const unsigned short* src = aggb + (rowBase + node) * H + (seg - 8) * 16;
            *(short8*)&a_stage[node * 264 + 128 + (seg - 8) * 16]     = *(const short8*)src;
            *(short8*)&a_stage[node * 264 + 128 + (seg - 8) * 16 + 8] = *(const short8*)(src + 8);
        }
        __syncthreads();

        short8 afr[8];
#pragma unroll
        for (int kst = 0; kst < 8; ++kst)
            afr[kst] = *(const short8*)(&a_stage[col * 264 + kst * 32 + quad * 8]);

        f32x4 acc0 = {0.f,0.f,0.f,0.f};
        f32x4 acc1 = {0.f,0.f,0.f,0.f};
#pragma unroll
        for (int kst = 0; kst < 8; ++kst) {
            acc0 = __builtin_amdgcn_mfma_f32_16x16x32_bf16(afr[kst], bfrag[0][kst], acc0, 0, 0, 0);
            acc1 = __builtin_amdgcn_mfma_f32_16x16x32_bf16(afr[kst], bfrag[1][kst], acc1, 0, 0, 0);
        }

#pragma unroll
        for (int s = 0; s < 2; ++s) {
            const int h = (wave * 2 + s) * 16 + col;
            f32x4 a = s ? acc1 : acc0;
#pragma unroll
            for (int r = 0; r < 4; ++r) {
                const int m = quad * 4 + r;
                float v = a[r] + bias[s];
                o_stage[m * 132 + h] = v > 0.f ? v : 0.f;
            }
        }
        __syncthreads();

        float v[8];
        float s1 = 0.f, s2 = 0.f;
#pragma unroll
        for (int j = 0; j < 8; ++j) {
            v[j] = o_stage[lnode * 132 + f0 + j];
            s1 += v[j];
            s2 += v[j] * v[j];
        }
#pragma unroll
        for (int m = 1; m < 16; m <<= 1) {
            s1 += __shfl_xor(s1, m, 64);
            s2 += __shfl_xor(s2, m, 64);
        }
        const float mu = s1 * (1.f / 128.f);
        const float var = s2 * (1.f / 128.f) - mu * mu;
        const float rstd = rsqrtf(var + 1e-5f);

        f32x4 o0, o1;
        o0.x = (v[0] - mu) * rstd * g0.x + be0.x;
        o0.y = (v[1] - mu) * rstd * g0.y + be0.y;
        o0.z = (v[2] - mu) * rstd * g0.z + be0.z;
        o0.w = (v[3] - mu) * rstd * g0.w + be0.w;
        o1.x = (v[4] - mu) * rstd * g1.x + be1.x;
        o1.y = (v[5] - mu) * rstd * g1.y + be1.y;
        o1.z = (v[6] - mu) * rstd * g1.z + be1.z;
        o1.w = (v[7] - mu) * rstd * g1.w + be1.w;

        float* dst = out + (rowBase + lnode) * H + f0;
        __builtin_nontemporal_store(o0, (f32x4*)dst);
        __builtin_nontemporal_store(o1, (f32x4*)(dst + 4));
    }
}

// ---------------------------------------------------------------------------
// Tier-C fallback: atomic scatter + fp32 gemm (agg staged in d_out).
// ---------------------------------------------------------------------------
__global__ __launch_bounds__(256) void scatter_kernel(
    const float* __restrict__ x, const int* __restrict__ ei,
    const int* __restrict__ et, const float* __restrict__ emb,
    float* __restrict__ agg, int E)
{
    int g = blockIdx.x * 256 + threadIdx.x;
    int e = g >> 5;
    int l = g & 31;
    if (e >= E) return;
    int src = ei[e];
    int dst = ei[E + e];
    int t   = et[e];
    f32x4 xv = *(const f32x4*)(x   + (size_t)src * H + l * 4);
    f32x4 ev = *(const f32x4*)(emb + (size_t)t   * H + l * 4);
    float* b = agg + (size_t)dst * H + l * 4;
    atomicAdd(b + 0, xv.x + ev.x);
    atomicAdd(b + 1, xv.y + ev.y);
    atomicAdd(b + 2, xv.z + ev.z);
    atomicAdd(b + 3, xv.w + ev.w);
}

__global__ __launch_bounds__(256) void gemm_ln_f32_kernel(
    const float* __restrict__ x,
    const float* __restrict__ Wself, const float* __restrict__ bself,
    const float* __restrict__ Wmsg, const float* __restrict__ bmsg,
    const float* __restrict__ gamma, const float* __restrict__ beta,
    float* __restrict__ out, int nTiles)
{
    __shared__ __align__(16) short a_stage[TM * 264];
    __shared__ __align__(16) float o_stage[TM * 132];

    const int tid  = threadIdx.x;
    const int wave = tid >> 6;
    const int lane = tid & 63;
    const int col  = lane & 15;
    const int quad = lane >> 4;

    short8 bfrag[2][8];
    float bias[2];
#pragma unroll
    for (int s = 0; s < 2; ++s) {
        const int h = (wave * 2 + s) * 16 + col;
        bias[s] = bself[h] + bmsg[h];
#pragma unroll
        for (int kst = 0; kst < 8; ++kst) {
            const float* W = (kst < 4) ? Wself : Wmsg;
            const int k0 = (kst & 3) * 32 + quad * 8;
            const float* p = W + (size_t)h * H + k0;
            bfrag[s][kst] = cvt8(*(const f32x4*)p, *(const f32x4*)(p + 4));
        }
    }

    const int lnode = tid >> 4;
    const int f0 = (tid & 15) * 8;
    f32x4 g0  = *(const f32x4*)(gamma + f0);
    f32x4 g1  = *(const f32x4*)(gamma + f0 + 4);
    f32x4 be0 = *(const f32x4*)(beta + f0);
    f32x4 be1 = *(const f32x4*)(beta + f0 + 4);

    for (int tile = blockIdx.x; tile < nTiles; tile += gridDim.x) {
        const size_t rowBase = (size_t)tile * TM;
        {
            const int node = tid >> 4;
            const int seg  = tid & 15;
            const int k0   = seg * 16;
            const float* src = (seg < 8)
                ? (x   + (rowBase + node) * H + k0)
                : (out + (rowBase + node) * H + (k0 - 128));
            f32x4 v0 = ((const f32x4*)src)[0];
            f32x4 v1 = ((const f32x4*)src)[1];
            f32x4 v2 = ((const f32x4*)src)[2];
            f32x4 v3 = ((const f32x4*)src)[3];
            *(short8*)(&a_stage[node * 264 + k0])     = cvt8(v0, v1);
            *(short8*)(&a_stage[node * 264 + k0 + 8]) = cvt8(v2, v3);
        }
        __syncthreads();

        short8 afr[8];
#pragma unroll
        for (int kst = 0; kst < 8; ++kst)
            afr[kst] = *(const short8*)(&a_stage[col * 264 + kst * 32 + quad * 8]);

        f32x4 acc0 = {0.f,0.f,0.f,0.f};
        f32x4 acc1 = {0.f,0.f,0.f,0.f};
#pragma unroll
        for (int kst = 0; kst < 8; ++kst) {
            acc0 = __builtin_amdgcn_mfma_f32_16x16x32_bf16(afr[kst], bfrag[0][kst], acc0, 0, 0, 0);
            acc1 = __builtin_amdgcn_mfma_f32_16x16x32_bf16(afr[kst], bfrag[1][kst], acc1, 0, 0, 0);
        }

#pragma unroll
        for (int s = 0; s < 2; ++s) {
            const int h = (wave * 2 + s) * 16 + col;
            f32x4 a = s ? acc1 : acc0;
#pragma unroll
            for (int r = 0; r < 4; ++r) {
                const int m = quad * 4 + r;
                float v = a[r] + bias[s];
                o_stage[m * 132 + h] = v > 0.f ? v : 0.f;
            }
        }
        __syncthreads();

        float v[8];
        float s1 = 0.f, s2 = 0.f;
#pragma unroll
        for (int j = 0; j < 8; ++j) {
            v[j] = o_stage[lnode * 132 + f0 + j];
            s1 += v[j];
            s2 += v[j] * v[j];
        }
#pragma unroll
        for (int m = 1; m < 16; m <<= 1) {
            s1 += __shfl_xor(s1, m, 64);
            s2 += __shfl_xor(s2, m, 64);
        }
        const float mu = s1 * (1.f / 128.f);
        const float var = s2 * (1.f / 128.f) - mu * mu;
        const float rstd = rsqrtf(var + 1e-5f);

        f32x4 o0, o1;
        o0.x = (v[0] - mu) * rstd * g0.x + be0.x;
        o0.y = (v[1] - mu) * rstd * g0.y + be0.y;
        o0.z = (v[2] - mu) * rstd * g0.z + be0.z;
        o0.w = (v[3] - mu) * rstd * g0.w + be0.w;
        o1.x = (v[4] - mu) * rstd * g1.x + be1.x;
        o1.y = (v[5] - mu) * rstd * g1.y + be1.y;
        o1.z = (v[6] - mu) * rstd * g1.z + be1.z;
        o1.w = (v[7] - mu) * rstd * g1.w + be1.w;

        float* dst = out + (rowBase + lnode) * H + f0;
        *(f32x4*)(dst)     = o0;
        *(f32x4*)(dst + 4) = o1;
    }
}

extern "C" void kernel_launch(void* const* d_in, const int* in_sizes, int n_in,
                              void* d_out, int out_size, void* d_ws, size_t ws_size,
                              hipStream_t stream) {
    const float* x     = (const float*)d_in[0];
    const int*   ei    = (const int*)d_in[1];
    const int*   et    = (const int*)d_in[2];
    const float* emb   = (const float*)d_in[3];
    const float* Wself = (const float*)d_in[4];
    const float* bself = (const float*)d_in[5];
    const float* Wmsg  = (const float*)d_in[6];
    const float* bmsg  = (const float*)d_in[7];
    const float* gamma = (const float*)d_in[8];
    const float* beta  = (const float*)d_in[9];
    float* out = (float*)d_out;

    const int E = in_sizes[2];
    const int N = in_sizes[0] / H;
    const int T = in_sizes[3] / H;
    const int nTiles = N / TM;

    auto rnd = [](size_t b) { return (b + 255) & ~(size_t)255; };
    const size_t sz_xb    = rnd((size_t)N * H * 2);
    const size_t sz_embb  = rnd((size_t)T * H * 2);
    const size_t sz_agg   = rnd((size_t)N * H * 2);
    const size_t sz_bkt16 = rnd((size_t)N * BSTR16 * 4);           // tier A
    const size_t sz_ovf   = rnd((size_t)(8 + 2 * OVFCAP) * 4);     // tier A spill
    const size_t sz_cnt   = rnd((size_t)N * 4);
    const size_t sz_bkt24 = rnd((size_t)N * MAXDEG * 4);           // tier B
    const size_t needA = sz_xb + sz_embb + sz_agg + sz_bkt16 + sz_ovf;
    const size_t needB = sz_agg + sz_cnt + sz_bkt24;

    const bool okT = (T <= 16) && (N <= (1 << 18));
    const bool tierA = okT && (ws_size >= needA) && (N % 32 == 0);
    const bool tierB = okT && (ws_size >= needB) && (N % TM == 0);

    if (tierA) {
        uint8_t* p = (uint8_t*)d_ws;
        unsigned short* xb   = (unsigned short*)p;  p += sz_xb;
        unsigned short* embb = (unsigned short*)p;  p += sz_embb;
        unsigned short* aggb = (unsigned short*)p;  p += sz_agg;
        int* bucket = (int*)p;                      p += sz_bkt16;
        int* ovf    = (int*)p;

        hipMemsetAsync(bucket, 0, sz_bkt16 + sz_ovf, stream);

        const int t8x = N * H / 8, t8e = T * H / 8;
        int prepWork = (t8x + t8e) > E ? (t8x + t8e) : E;
        prep_kernel<<<(prepWork + 255) / 256, 256, 0, stream>>>(
            x, emb, xb, embb, ei, et, bucket, ovf, t8x, t8e, E);

        const int nGroups = N >> 4;
        int aggGrid = nGroups < 6250 ? nGroups : 6250;
        aggregate_bf16_kernel<<<aggGrid, 256, 0, stream>>>(
            xb, embb, bucket, ovf, ei, et, aggb, N, E, T);

        const int nSuper = N / 32;
        int gemmGrid = nSuper < 1024 ? nSuper : 1024;   // 4 blocks/CU, all resident
        gemm_ln32_kernel<<<gemmGrid, 256, 0, stream>>>(
            xb, aggb, Wself, bself, Wmsg, bmsg, gamma, beta, out, nSuper);
    } else if (tierB) {
        uint8_t* p = (uint8_t*)d_ws;
        unsigned short* aggb = (unsigned short*)p;  p += sz_agg;
        int* cnt    = (int*)p;                      p += sz_cnt;
        int* bucket = (int*)p;

        hipMemsetAsync(cnt, 0, (size_t)N * sizeof(int), stream);

        if (E > 0) {
            prep_edges_kernel<<<(E + 255) / 256, 256, 0, stream>>>(
                ei, et, cnt, bucket, E);
        }
        const int nGroups = N >> 4;
        int aggGrid = nGroups < 4096 ? nGroups : 4096;
        aggregate_f32_kernel<<<aggGrid, 256, 0, stream>>>(
            x, emb, cnt, bucket, ei, et, aggb, N, E, T);

        int gemmGrid = nTiles < 2048 ? nTiles : 2048;
        gemm_ln16_kernel<<<gemmGrid, 256, 0, stream>>>(
            x, aggb, Wself, bself, Wmsg, bmsg, gamma, beta, out, nTiles);
    } else {
        hipMemsetAsync(out, 0, (size_t)N * H * sizeof(float), stream);
        const long long sthreads = (long long)E * 32;
        scatter_kernel<<<(int)((sthreads + 255) / 256), 256, 0, stream>>>(
            x, ei, et, emb, out, E);
        int grid = 2500;
        if (grid > nTiles) grid = nTiles;
        gemm_ln_f32_kernel<<<grid, 256, 0, stream>>>(
            x, Wself, bself, Wmsg, bmsg, gamma, beta, out, nTiles);
    }
}

// Round 11
// 293.274 us; speedup vs baseline: 1.0934x; 1.0934x over previous
//
#include <hip/hip_runtime.h>
#include <stdint.h>

#define H 128
#define TM 16
#define MAXDEG 24        // tier B layout
#define BSTR16 16        // tier A bucket row: [count, e0..e14] = 16 ints = one 64B line
#define OVFCAP 4096      // tier A overflow side-array capacity (deg>15 spill)

typedef __attribute__((ext_vector_type(8))) short short8;
typedef __attribute__((ext_vector_type(4))) float f32x4;
typedef __attribute__((ext_vector_type(4))) int i32x4;

__device__ __forceinline__ unsigned short f2bf(float f) {
    union { float f; unsigned u; } v; v.f = f;
    unsigned u = v.u;
    u += 0x7fffu + ((u >> 16) & 1u);   // round-to-nearest-even
    return (unsigned short)(u >> 16);
}

__device__ __forceinline__ float bf2f(unsigned short u) {
    union { unsigned u; float f; } v; v.u = ((unsigned)u) << 16; return v.f;
}

__device__ __forceinline__ short8 cvt8(f32x4 a, f32x4 b) {
    short8 r;
    r[0] = (short)f2bf(a.x); r[1] = (short)f2bf(a.y);
    r[2] = (short)f2bf(a.z); r[3] = (short)f2bf(a.w);
    r[4] = (short)f2bf(b.x); r[5] = (short)f2bf(b.y);
    r[6] = (short)f2bf(b.z); r[7] = (short)f2bf(b.w);
    return r;
}

__device__ __forceinline__ void gadd(int entry, const unsigned short* xb,
                                     const short* emb_s, int l, float* acc) {
    int s = entry & 0x3FFFF, t = entry >> 18;
    short8 xv = *(const short8*)(xb + (size_t)s * H + l * 8);
    short8 ev = *(const short8*)&emb_s[t * 136 + l * 8];
#pragma unroll
    for (int j = 0; j < 8; ++j)
        acc[j] += bf2f((unsigned short)xv[j]) + bf2f((unsigned short)ev[j]);
}

__device__ __forceinline__ void csr_insert(int src, int dst, int t,
                                           int* bucket, int* ovf) {
    int entry = src | (t << 18);
    int* row = bucket + ((size_t)dst << 4);
    int pos = atomicAdd(row, 1);
    if (pos < 15) {
        row[1 + pos] = entry;
    } else {
        int j = atomicAdd(ovf, 1);
        if (j < OVFCAP) { ovf[8 + 2 * j] = dst; ovf[8 + 2 * j + 1] = entry; }
    }
}

// ---------------------------------------------------------------------------
// Tier A prep: one conversion unit per thread (full occupancy) + edges sliced
// UNIFORMLY across all blocks (~47/block) so every block's ~2 atomic chains
// overlap its 256 conversion threads (R10: confirmed win). NT LOADS only:
// x/emb are read-once. xb/embb use REGULAR stores so the converted arrays
// stay L2/L3-resident for aggregate's random gathers (R10 lesson: NT stores
// bypassed L3 and cost aggregate ~20us of cold HBM first-touch).
// Bucket row = 16 ints (one 64B line): row[0]=count, row[1+pos]=entry.
// ---------------------------------------------------------------------------
__global__ __launch_bounds__(256) void prep_kernel(
    const float* __restrict__ x, const float* __restrict__ emb,
    unsigned short* __restrict__ xb, unsigned short* __restrict__ embb,
    const int* __restrict__ ei, const int* __restrict__ et,
    int* __restrict__ bucket, int* __restrict__ ovf,
    int total8x, int total8e, int E)
{
    const int tid = threadIdx.x;
    const int i = blockIdx.x * 256 + tid;

    // ---- this block's edge slice (uniform across grid) ----
    const int nb = gridDim.x;
    const int e0 = (int)(((long long)blockIdx.x * E) / nb);
    const int e1 = (int)(((long long)(blockIdx.x + 1) * E) / nb);

    // ---- issue first-round edge loads early (overlap with conversion) ----
    int src = 0, dst = 0, t = 0;
    int e = e0 + tid;
    const bool hasE = (e < e1);
    if (hasE) {
        src = ei[e];
        dst = ei[E + e];
        t   = et[e];
    }

    // ---- streaming conversion (NT loads; regular stores -> L3-resident) ----
    if (i < total8x) {
        f32x4 a = __builtin_nontemporal_load(((const f32x4*)x) + 2 * i);
        f32x4 b = __builtin_nontemporal_load(((const f32x4*)x) + 2 * i + 1);
        ((short8*)xb)[i] = cvt8(a, b);
    } else if (i < total8x + total8e) {
        int j = i - total8x;
        f32x4 a = __builtin_nontemporal_load(((const f32x4*)emb) + 2 * j);
        f32x4 b = __builtin_nontemporal_load(((const f32x4*)emb) + 2 * j + 1);
        ((short8*)embb)[j] = cvt8(a, b);
    }

    // ---- CSR insert (atomic latency hidden under the conversion above) ----
    if (hasE) csr_insert(src, dst, t, bucket, ovf);

    // rare tail: slice larger than one thread-round (not at default shapes)
    for (e = e0 + 256 + tid; e < e1; e += 256) {
        csr_insert(ei[e], ei[E + e], et[e], bucket, ovf);
    }
}

// Tier B prep: CSR only (old separate cnt/bucket layout).
__global__ __launch_bounds__(256) void prep_edges_kernel(
    const int* __restrict__ ei, const int* __restrict__ et,
    int* __restrict__ cnt, int* __restrict__ bucket, int E)
{
    int e = blockIdx.x * 256 + threadIdx.x;
    if (e >= E) return;
    int src = ei[e];
    int dst = ei[E + e];
    int t   = et[e];
    int pos = atomicAdd(&cnt[dst], 1);
    if (pos < MAXDEG) bucket[(size_t)dst * MAXDEG + pos] = src | (t << 18);
}

// ---------------------------------------------------------------------------
// Tier A aggregate: bf16 gather, fp32 accumulate, bf16 write. (R6-R8 proven)
// One 16-lane group per node. Header quad = count + entries 0..2.
// deg>15: 15 inline entries + ovf scan. Spill-overflow: full E-scan.
// ---------------------------------------------------------------------------
__global__ __launch_bounds__(256) void aggregate_bf16_kernel(
    const unsigned short* __restrict__ xb, const unsigned short* __restrict__ embb,
    const int* __restrict__ bucket, const int* __restrict__ ovf,
    const int* __restrict__ ei, const int* __restrict__ et,
    unsigned short* __restrict__ aggb, int N, int E, int T)
{
    __shared__ __align__(16) short emb_s[16 * 136];   // padded stride 136

    const int tid = threadIdx.x;
    const int l   = tid & 15;      // feature chunk: l*8 .. l*8+7
    if (tid < T * 16) {
        int t = tid >> 4;
        *(short8*)&emb_s[t * 136 + l * 8] = *(const short8*)(embb + t * H + l * 8);
    }
    __syncthreads();

    const int nGroups = N >> 4;
    for (int g = blockIdx.x; g < nGroups; g += gridDim.x) {
        const int node = (g << 4) + (tid >> 4);

        const int* row = bucket + ((size_t)node << 4);
        i32x4 q = *(const i32x4*)row;   // count + entries 0,1,2
        const int c = q.x;

        float acc[8] = {0.f, 0.f, 0.f, 0.f, 0.f, 0.f, 0.f, 0.f};

        bool fullscan = false;
        int cc = c, nov = 0;
        if (c > 15) {
            nov = ovf[0];
            if (nov > OVFCAP) fullscan = true;   // spill overflowed: rescan
            cc = 15;
        }

        if (!fullscan) {
            {
                const bool b0 = cc > 0, b1 = cc > 1, b2 = cc > 2;
                short8 xv0, xv1, xv2, ev0, ev1, ev2;
                if (b0) {
                    int s = q.y & 0x3FFFF, t = q.y >> 18;
                    xv0 = *(const short8*)(xb + (size_t)s * H + l * 8);
                    ev0 = *(const short8*)&emb_s[t * 136 + l * 8];
                }
                if (b1) {
                    int s = q.z & 0x3FFFF, t = q.z >> 18;
                    xv1 = *(const short8*)(xb + (size_t)s * H + l * 8);
                    ev1 = *(const short8*)&emb_s[t * 136 + l * 8];
                }
                if (b2) {
                    int s = q.w & 0x3FFFF, t = q.w >> 18;
                    xv2 = *(const short8*)(xb + (size_t)s * H + l * 8);
                    ev2 = *(const short8*)&emb_s[t * 136 + l * 8];
                }
                if (b0) {
#pragma unroll
                    for (int j = 0; j < 8; ++j) acc[j] += bf2f((unsigned short)xv0[j]) + bf2f((unsigned short)ev0[j]);
                }
                if (b1) {
#pragma unroll
                    for (int j = 0; j < 8; ++j) acc[j] += bf2f((unsigned short)xv1[j]) + bf2f((unsigned short)ev1[j]);
                }
                if (b2) {
#pragma unroll
                    for (int j = 0; j < 8; ++j) acc[j] += bf2f((unsigned short)xv2[j]) + bf2f((unsigned short)ev2[j]);
                }
            }
            for (int i0 = 3; i0 < cc; i0 += 4) {
                i32x4 p = *(const i32x4*)(row + 1 + i0);   // entries i0..i0+3
                const int rem = cc - i0;
                const bool h1 = rem > 1, h2 = rem > 2, h3 = rem > 3;
                short8 xv0, xv1, xv2, xv3, ev0, ev1, ev2, ev3;
                {
                    int s = p.x & 0x3FFFF, t = p.x >> 18;
                    xv0 = *(const short8*)(xb + (size_t)s * H + l * 8);
                    ev0 = *(const short8*)&emb_s[t * 136 + l * 8];
                }
                if (h1) {
                    int s = p.y & 0x3FFFF, t = p.y >> 18;
                    xv1 = *(const short8*)(xb + (size_t)s * H + l * 8);
                    ev1 = *(const short8*)&emb_s[t * 136 + l * 8];
                }
                if (h2) {
                    int s = p.z & 0x3FFFF, t = p.z >> 18;
                    xv2 = *(const short8*)(xb + (size_t)s * H + l * 8);
                    ev2 = *(const short8*)&emb_s[t * 136 + l * 8];
                }
                if (h3) {
                    int s = p.w & 0x3FFFF, t = p.w >> 18;
                    xv3 = *(const short8*)(xb + (size_t)s * H + l * 8);
                    ev3 = *(const short8*)&emb_s[t * 136 + l * 8];
                }
#pragma unroll
                for (int j = 0; j < 8; ++j) acc[j] += bf2f((unsigned short)xv0[j]) + bf2f((unsigned short)ev0[j]);
                if (h1) {
#pragma unroll
                    for (int j = 0; j < 8; ++j) acc[j] += bf2f((unsigned short)xv1[j]) + bf2f((unsigned short)ev1[j]);
                }
                if (h2) {
#pragma unroll
                    for (int j = 0; j < 8; ++j) acc[j] += bf2f((unsigned short)xv2[j]) + bf2f((unsigned short)ev2[j]);
                }
                if (h3) {
#pragma unroll
                    for (int j = 0; j < 8; ++j) acc[j] += bf2f((unsigned short)xv3[j]) + bf2f((unsigned short)ev3[j]);
                }
            }
            if (c > 15) {
                for (int j = 0; j < nov; ++j) {
                    if (ovf[8 + 2 * j] == node) gadd(ovf[8 + 2 * j + 1], xb, emb_s, l, acc);
                }
            }
        } else {
            for (int e = 0; e < E; ++e) {
                if (ei[E + e] == node) gadd(ei[e] | (et[e] << 18), xb, emb_s, l, acc);
            }
        }

        short8 r;
#pragma unroll
        for (int j = 0; j < 8; ++j) r[j] = (short)f2bf(acc[j]);
        *(short8*)(aggb + (size_t)node * H + l * 8) = r;
    }
}

// ---------------------------------------------------------------------------
// Tier A GEMM+LN: R5 structure (2 barriers, separate a/o buffers). Grid 1024
// = 4 blocks/CU (LDS cap), all resident; ~6 tiles/block amortizes the weight
// prologue. LN: line-complete NT stores. (R8-proven, ~55us)
// ---------------------------------------------------------------------------
__global__ __launch_bounds__(256) void gemm_ln32_kernel(
    const unsigned short* __restrict__ xb, const unsigned short* __restrict__ aggb,
    const float* __restrict__ Wself, const float* __restrict__ bself,
    const float* __restrict__ Wmsg, const float* __restrict__ bmsg,
    const float* __restrict__ gamma, const float* __restrict__ beta,
    float* __restrict__ out, int nSuper)
{
    __shared__ __align__(16) short a_stage[32 * 264];  // 32 x (256+8 pad) bf16
    __shared__ __align__(16) float o_stage[32 * 132];  // 32 x (128+4 pad) f32

    const int tid  = threadIdx.x;
    const int wave = tid >> 6;
    const int lane = tid & 63;
    const int col  = lane & 15;
    const int quad = lane >> 4;

    // ---- B fragments (weights, bf16) into registers; once per block ----
    short8 bfrag[2][8];
    float bias[2];
#pragma unroll
    for (int s = 0; s < 2; ++s) {
        const int h = (wave * 2 + s) * 16 + col;
        bias[s] = bself[h] + bmsg[h];
#pragma unroll
        for (int kst = 0; kst < 8; ++kst) {
            const float* W = (kst < 4) ? Wself : Wmsg;
            const int k0 = (kst & 3) * 32 + quad * 8;
            const float* p = W + (size_t)h * H + k0;
            bfrag[s][kst] = cvt8(*(const f32x4*)p, *(const f32x4*)(p + 4));
        }
    }

    // LN mapping: 16 lanes/row; lane l owns feats [l4,+4) and [64+l4,+4)
    const int lrow = tid >> 4;           // 0..15 (row within 16-row half)
    const int l4 = (tid & 15) * 4;
    f32x4 g0  = *(const f32x4*)(gamma + l4);
    f32x4 g1  = *(const f32x4*)(gamma + 64 + l4);
    f32x4 be0 = *(const f32x4*)(beta + l4);
    f32x4 be1 = *(const f32x4*)(beta + 64 + l4);

    const int srow = tid >> 3;   // 0..31: staging row
    const int sq   = tid & 7;    // 0..7

    for (int st = blockIdx.x; st < nSuper; st += gridDim.x) {
        const size_t rowBase = (size_t)st * 32;

        // ---- stage 32x256 bf16: sq<4 -> xb chunks, sq>=4 -> aggb chunks ----
        {
            const unsigned short* src = (sq < 4)
                ? (xb   + (rowBase + srow) * H + sq * 32)
                : (aggb + (rowBase + srow) * H + (sq - 4) * 32);
            short* dstl = &a_stage[srow * 264 + (sq & 3) * 32 + ((sq >> 2) << 7)];
            *(short8*)(dstl)      = ((const short8*)src)[0];
            *(short8*)(dstl + 8)  = ((const short8*)src)[1];
            *(short8*)(dstl + 16) = ((const short8*)src)[2];
            *(short8*)(dstl + 24) = ((const short8*)src)[3];
        }
        __syncthreads();   // sync#1: a_stage visible

        // ---- MFMA: 2 row-tiles x 2 feature-halves, K=256 ----
        f32x4 acc00 = {0.f,0.f,0.f,0.f}, acc01 = {0.f,0.f,0.f,0.f};
        f32x4 acc10 = {0.f,0.f,0.f,0.f}, acc11 = {0.f,0.f,0.f,0.f};
        {
            short8 afr[8];
#pragma unroll
            for (int kst = 0; kst < 8; ++kst)
                afr[kst] = *(const short8*)&a_stage[col * 264 + kst * 32 + quad * 8];
#pragma unroll
            for (int kst = 0; kst < 8; ++kst) {
                acc00 = __builtin_amdgcn_mfma_f32_16x16x32_bf16(afr[kst], bfrag[0][kst], acc00, 0, 0, 0);
                acc01 = __builtin_amdgcn_mfma_f32_16x16x32_bf16(afr[kst], bfrag[1][kst], acc01, 0, 0, 0);
            }
#pragma unroll
            for (int kst = 0; kst < 8; ++kst)
                afr[kst] = *(const short8*)&a_stage[(16 + col) * 264 + kst * 32 + quad * 8];
#pragma unroll
            for (int kst = 0; kst < 8; ++kst) {
                acc10 = __builtin_amdgcn_mfma_f32_16x16x32_bf16(afr[kst], bfrag[0][kst], acc10, 0, 0, 0);
                acc11 = __builtin_amdgcn_mfma_f32_16x16x32_bf16(afr[kst], bfrag[1][kst], acc11, 0, 0, 0);
            }
        }

        // ---- bias + relu -> o_stage ----
        {
            const int h0 = (wave * 2) * 16 + col;
            const int h1 = h0 + 16;
#pragma unroll
            for (int r = 0; r < 4; ++r) {
                const int m = quad * 4 + r;
                float v;
                v = acc00[r] + bias[0]; o_stage[m * 132 + h0]        = v > 0.f ? v : 0.f;
                v = acc01[r] + bias[1]; o_stage[m * 132 + h1]        = v > 0.f ? v : 0.f;
                v = acc10[r] + bias[0]; o_stage[(16 + m) * 132 + h0] = v > 0.f ? v : 0.f;
                v = acc11[r] + bias[1]; o_stage[(16 + m) * 132 + h1] = v > 0.f ? v : 0.f;
            }
        }
        __syncthreads();   // sync#2: o_stage visible; all a_stage reads retired

        // ---- LayerNorm: two 16-row passes; line-complete NT stores ----
#pragma unroll
        for (int half = 0; half < 2; ++half) {
            const int row = half * 16 + lrow;
            const float* orow = &o_stage[row * 132];
            f32x4 va = *(const f32x4*)(orow + l4);        // feats l4..l4+3
            f32x4 vb = *(const f32x4*)(orow + 64 + l4);   // feats 64+l4..

            float s1 = (va.x + va.y + va.z + va.w) + (vb.x + vb.y + vb.z + vb.w);
            float s2 = va.x*va.x + va.y*va.y + va.z*va.z + va.w*va.w
                     + vb.x*vb.x + vb.y*vb.y + vb.z*vb.z + vb.w*vb.w;
#pragma unroll
            for (int m = 1; m < 16; m <<= 1) {
                s1 += __shfl_xor(s1, m, 64);
                s2 += __shfl_xor(s2, m, 64);
            }
            const float mu = s1 * (1.f / 128.f);
            const float var = s2 * (1.f / 128.f) - mu * mu;
            const float rstd = rsqrtf(var + 1e-5f);

            f32x4 o0, o1;
            o0.x = (va.x - mu) * rstd * g0.x + be0.x;
            o0.y = (va.y - mu) * rstd * g0.y + be0.y;
            o0.z = (va.z - mu) * rstd * g0.z + be0.z;
            o0.w = (va.w - mu) * rstd * g0.w + be0.w;
            o1.x = (vb.x - mu) * rstd * g1.x + be1.x;
            o1.y = (vb.y - mu) * rstd * g1.y + be1.y;
            o1.z = (vb.z - mu) * rstd * g1.z + be1.z;
            o1.w = (vb.w - mu) * rstd * g1.w + be1.w;

            float* dst = out + (rowBase + row) * H;
            __builtin_nontemporal_store(o0, (f32x4*)(dst + l4));
            __builtin_nontemporal_store(o1, (f32x4*)(dst + 64 + l4));
        }
        // no trailing barrier: next-iter a_stage writes happen only after
        // every wave passed sync#2.
    }
}

// ---------------------------------------------------------------------------
// Tier B (round-1 proven): fp32 gather aggregate + 16-row gemm reading fp32 x.
// ---------------------------------------------------------------------------
__global__ __launch_bounds__(256) void aggregate_f32_kernel(
    const float* __restrict__ x, const float* __restrict__ emb,
    const int* __restrict__ cnt, const int* __restrict__ bucket,
    const int* __restrict__ ei, const int* __restrict__ et,
    unsigned short* __restrict__ aggb, int N, int E, int T)
{
    __shared__ __align__(16) float emb_s[16 * 132];

    const int tid = threadIdx.x;
    for (int i = tid; i < T * H; i += 256)
        emb_s[(i >> 7) * 132 + (i & 127)] = emb[i];
    __syncthreads();

    const int l = tid & 15;
    const int nGroups = N >> 4;

    for (int g = blockIdx.x; g < nGroups; g += gridDim.x) {
        const int node = (g << 4) + (tid >> 4);
        const int* b = bucket + (size_t)node * MAXDEG;
        i32x4 p = *(const i32x4*)b;
        const int c = cnt[node];

        f32x4 acc0 = {0.f,0.f,0.f,0.f};
        f32x4 acc1 = {0.f,0.f,0.f,0.f};

        if (c <= MAXDEG) {
            for (int i0 = 0; i0 < c; i0 += 4) {
                if (i0 > 0) p = *(const i32x4*)(b + i0);
                const int rem = c - i0;
                const bool h1 = rem > 1, h2 = rem > 2, h3 = rem > 3;
                f32x4 x00,x01,e00,e01,x10,x11,e10,e11,x20,x21,e20,e21,x30,x31,e30,e31;
                {
                    int s = p.x & 0x3FFFF, t = p.x >> 18;
                    const float* xp = x + (size_t)s * H + l * 8;
                    const float* ep = emb_s + t * 132 + l * 8;
                    x00 = *(const f32x4*)xp; x01 = *(const f32x4*)(xp + 4);
                    e00 = *(const f32x4*)ep; e01 = *(const f32x4*)(ep + 4);
                }
                if (h1) {
                    int s = p.y & 0x3FFFF, t = p.y >> 18;
                    const float* xp = x + (size_t)s * H + l * 8;
                    const float* ep = emb_s + t * 132 + l * 8;
                    x10 = *(const f32x4*)xp; x11 = *(const f32x4*)(xp + 4);
                    e10 = *(const f32x4*)ep; e11 = *(const f32x4*)(ep + 4);
                }
                if (h2) {
                    int s = p.z & 0x3FFFF, t = p.z >> 18;
                    const float* xp = x + (size_t)s * H + l * 8;
                    const float* ep = emb_s + t * 132 + l * 8;
                    x20 = *(const f32x4*)xp; x21 = *(const f32x4*)(xp + 4);
                    e20 = *(const f32x4*)ep; e21 = *(const f32x4*)(ep + 4);
                }
                if (h3) {
                    int s = p.w & 0x3FFFF, t = p.w >> 18;
                    const float* xp = x + (size_t)s * H + l * 8;
                    const float* ep = emb_s + t * 132 + l * 8;
                    x30 = *(const f32x4*)xp; x31 = *(const f32x4*)(xp + 4);
                    e30 = *(const f32x4*)ep; e31 = *(const f32x4*)(ep + 4);
                }
                acc0 += x00 + e00;  acc1 += x01 + e01;
                if (h1) { acc0 += x10 + e10;  acc1 += x11 + e11; }
                if (h2) { acc0 += x20 + e20;  acc1 += x21 + e21; }
                if (h3) { acc0 += x30 + e30;  acc1 += x31 + e31; }
            }
        } else {
            for (int e = 0; e < E; ++e) {
                if (ei[E + e] == node) {
                    int s = ei[e], t = et[e];
                    const float* xp = x + (size_t)s * H + l * 8;
                    const float* ep = emb_s + t * 132 + l * 8;
                    f32x4 a0 = *(const f32x4*)xp, a1 = *(const f32x4*)(xp + 4);
                    f32x4 b0 = *(const f32x4*)ep, b1 = *(const f32x4*)(ep + 4);
                    acc0 += a0 + b0;  acc1 += a1 + b1;
                }
            }
        }
        *(short8*)(aggb + (size_t)node * H + l * 8) = cvt8(acc0, acc1);
    }
}

__global__ __launch_bounds__(256) void gemm_ln16_kernel(
    const float* __restrict__ x, const unsigned short* __restrict__ aggb,
    const float* __restrict__ Wself, const float* __restrict__ bself,
    const float* __restrict__ Wmsg, const float* __restrict__ bmsg,
    const float* __restrict__ gamma, const float* __restrict__ beta,
    float* __restrict__ out, int nTiles)
{
    __shared__ __align__(16) short a_stage[TM * 264];
    __shared__ __align__(16) float o_stage[TM * 132];

    const int tid  = threadIdx.x;
    const int wave = tid >> 6;
    const int lane = tid & 63;
    const int col  = lane & 15;
    const int quad = lane >> 4;

    short8 bfrag[2][8];
    float bias[2];
#pragma unroll
    for (int s = 0; s < 2; ++s) {
        const int h = (wave * 2 + s) * 16 + col;
        bias[s] = bself[h] + bmsg[h];
#pragma unroll
        for (int kst = 0; kst < 8; ++kst) {
            const float* W = (kst < 4) ? Wself : Wmsg;
            const int k0 = (kst & 3) * 32 + quad * 8;
            const float* p = W + (size_t)h * H + k0;
            bfrag[s][kst] = cvt8(*(const f32x4*)p, *(const f32x4*)(p + 4));
        }
    }

    const int lnode = tid >> 4;
    const int f0 = (tid & 15) * 8;
    f32x4 g0  = *(const f32x4*)(gamma + f0);
    f32x4 g1  = *(const f32x4*)(gamma + f0 + 4);
    f32x4 be0 = *(const f32x4*)(beta + f0);
    f32x4 be1 = *(const f32x4*)(beta + f0 + 4);

    const int node = tid >> 4;
    const int seg  = tid & 15;

    for (int tile = blockIdx.x; tile < nTiles; tile += gridDim.x) {
        const size_t rowBase = (size_t)tile * TM;
        if (seg < 8) {
            const float* src = x + (rowBase + node) * H + seg * 16;
            f32x4 v0 = ((const f32x4*)src)[0];
            f32x4 v1 = ((const f32x4*)src)[1];
            f32x4 v2 = ((const f32x4*)src)[2];
            f32x4 v3 = ((const f32x4*)src)[3];
            *(short8*)&a_stage[node * 264 + seg * 16]     = cvt8(v0, v1);
            *(short8*)&a_stage[node * 264 + seg * 16 + 8] = cvt8(v2, v3);
        } else {
            const unsigned short* src = aggb + (rowBase + node) * H + (seg - 8) * 16;
            *(short8*)&a_stage[node * 264 + 128 + (seg - 8) * 16]     = *(const short8*)src;
            *(short8*)&a_stage[node * 264 + 128 + (seg - 8) * 16 + 8] = *(const short8*)(src + 8);
        }
        __syncthreads();

        short8 afr[8];
#pragma unroll
        for (int kst = 0; kst < 8; ++kst)
            afr[kst] = *(const short8*)(&a_stage[col * 264 + kst * 32 + quad * 8]);

        f32x4 acc0 = {0.f,0.f,0.f,0.f};
        f32x4 acc1 = {0.f,0.f,0.f,0.f};
#pragma unroll
        for (int kst = 0; kst < 8; ++kst) {
            acc0 = __builtin_amdgcn_mfma_f32_16x16x32_bf16(afr[kst], bfrag[0][kst], acc0, 0, 0, 0);
            acc1 = __builtin_amdgcn_mfma_f32_16x16x32_bf16(afr[kst], bfrag[1][kst], acc1, 0, 0, 0);
        }

#pragma unroll
        for (int s = 0; s < 2; ++s) {
            const int h = (wave * 2 + s) * 16 + col;
            f32x4 a = s ? acc1 : acc0;
#pragma unroll
            for (int r = 0; r < 4; ++r) {
                const int m = quad * 4 + r;
                float v = a[r] + bias[s];
                o_stage[m * 132 + h] = v > 0.f ? v : 0.f;
            }
        }
        __syncthreads();

        float v[8];
        float s1 = 0.f, s2 = 0.f;
#pragma unroll
        for (int j = 0; j < 8; ++j) {
            v[j] = o_stage[lnode * 132 + f0 + j];
            s1 += v[j];
            s2 += v[j] * v[j];
        }
#pragma unroll
        for (int m = 1; m < 16; m <<= 1) {
            s1 += __shfl_xor(s1, m, 64);
            s2 += __shfl_xor(s2, m, 64);
        }
        const float mu = s1 * (1.f / 128.f);
        const float var = s2 * (1.f / 128.f) - mu * mu;
        const float rstd = rsqrtf(var + 1e-5f);

        f32x4 o0, o1;
        o0.x = (v[0] - mu) * rstd * g0.x + be0.x;
        o0.y = (v[1] - mu) * rstd * g0.y + be0.y;
        o0.z = (v[2] - mu) * rstd * g0.z + be0.z;
        o0.w = (v[3] - mu) * rstd * g0.w + be0.w;
        o1.x = (v[4] - mu) * rstd * g1.x + be1.x;
        o1.y = (v[5] - mu) * rstd * g1.y + be1.y;
        o1.z = (v[6] - mu) * rstd * g1.z + be1.z;
        o1.w = (v[7] - mu) * rstd * g1.w + be1.w;

        float* dst = out + (rowBase + lnode) * H + f0;
        __builtin_nontemporal_store(o0, (f32x4*)dst);
        __builtin_nontemporal_store(o1, (f32x4*)(dst + 4));
    }
}

// ---------------------------------------------------------------------------
// Tier-C fallback: atomic scatter + fp32 gemm (agg staged in d_out).
// ---------------------------------------------------------------------------
__global__ __launch_bounds__(256) void scatter_kernel(
    const float* __restrict__ x, const int* __restrict__ ei,
    const int* __restrict__ et, const float* __restrict__ emb,
    float* __restrict__ agg, int E)
{
    int g = blockIdx.x * 256 + threadIdx.x;
    int e = g >> 5;
    int l = g & 31;
    if (e >= E) return;
    int src = ei[e];
    int dst = ei[E + e];
    int t   = et[e];
    f32x4 xv = *(const f32x4*)(x   + (size_t)src * H + l * 4);
    f32x4 ev = *(const f32x4*)(emb + (size_t)t   * H + l * 4);
    float* b = agg + (size_t)dst * H + l * 4;
    atomicAdd(b + 0, xv.x + ev.x);
    atomicAdd(b + 1, xv.y + ev.y);
    atomicAdd(b + 2, xv.z + ev.z);
    atomicAdd(b + 3, xv.w + ev.w);
}

__global__ __launch_bounds__(256) void gemm_ln_f32_kernel(
    const float* __restrict__ x,
    const float* __restrict__ Wself, const float* __restrict__ bself,
    const float* __restrict__ Wmsg, const float* __restrict__ bmsg,
    const float* __restrict__ gamma, const float* __restrict__ beta,
    float* __restrict__ out, int nTiles)
{
    __shared__ __align__(16) short a_stage[TM * 264];
    __shared__ __align__(16) float o_stage[TM * 132];

    const int tid  = threadIdx.x;
    const int wave = tid >> 6;
    const int lane = tid & 63;
    const int col  = lane & 15;
    const int quad = lane >> 4;

    short8 bfrag[2][8];
    float bias[2];
#pragma unroll
    for (int s = 0; s < 2; ++s) {
        const int h = (wave * 2 + s) * 16 + col;
        bias[s] = bself[h] + bmsg[h];
#pragma unroll
        for (int kst = 0; kst < 8; ++kst) {
            const float* W = (kst < 4) ? Wself : Wmsg;
            const int k0 = (kst & 3) * 32 + quad * 8;
            const float* p = W + (size_t)h * H + k0;
            bfrag[s][kst] = cvt8(*(const f32x4*)p, *(const f32x4*)(p + 4));
        }
    }

    const int lnode = tid >> 4;
    const int f0 = (tid & 15) * 8;
    f32x4 g0  = *(const f32x4*)(gamma + f0);
    f32x4 g1  = *(const f32x4*)(gamma + f0 + 4);
    f32x4 be0 = *(const f32x4*)(beta + f0);
    f32x4 be1 = *(const f32x4*)(beta + f0 + 4);

    for (int tile = blockIdx.x; tile < nTiles; tile += gridDim.x) {
        const size_t rowBase = (size_t)tile * TM;
        {
            const int node = tid >> 4;
            const int seg  = tid & 15;
            const int k0   = seg * 16;
            const float* src = (seg < 8)
                ? (x   + (rowBase + node) * H + k0)
                : (out + (rowBase + node) * H + (k0 - 128));
            f32x4 v0 = ((const f32x4*)src)[0];
            f32x4 v1 = ((const f32x4*)src)[1];
            f32x4 v2 = ((const f32x4*)src)[2];
            f32x4 v3 = ((const f32x4*)src)[3];
            *(short8*)(&a_stage[node * 264 + k0])     = cvt8(v0, v1);
            *(short8*)(&a_stage[node * 264 + k0 + 8]) = cvt8(v2, v3);
        }
        __syncthreads();

        short8 afr[8];
#pragma unroll
        for (int kst = 0; kst < 8; ++kst)
            afr[kst] = *(const short8*)(&a_stage[col * 264 + kst * 32 + quad * 8]);

        f32x4 acc0 = {0.f,0.f,0.f,0.f};
        f32x4 acc1 = {0.f,0.f,0.f,0.f};
#pragma unroll
        for (int kst = 0; kst < 8; ++kst) {
            acc0 = __builtin_amdgcn_mfma_f32_16x16x32_bf16(afr[kst], bfrag[0][kst], acc0, 0, 0, 0);
            acc1 = __builtin_amdgcn_mfma_f32_16x16x32_bf16(afr[kst], bfrag[1][kst], acc1, 0, 0, 0);
        }

#pragma unroll
        for (int s = 0; s < 2; ++s) {
            const int h = (wave * 2 + s) * 16 + col;
            f32x4 a = s ? acc1 : acc0;
#pragma unroll
            for (int r = 0; r < 4; ++r) {
                const int m = quad * 4 + r;
                float v = a[r] + bias[s];
                o_stage[m * 132 + h] = v > 0.f ? v : 0.f;
            }
        }
        __syncthreads();

        float v[8];
        float s1 = 0.f, s2 = 0.f;
#pragma unroll
        for (int j = 0; j < 8; ++j) {
            v[j] = o_stage[lnode * 132 + f0 + j];
            s1 += v[j];
            s2 += v[j] * v[j];
        }
#pragma unroll
        for (int m = 1; m < 16; m <<= 1) {
            s1 += __shfl_xor(s1, m, 64);
            s2 += __shfl_xor(s2, m, 64);
        }
        const float mu = s1 * (1.f / 128.f);
        const float var = s2 * (1.f / 128.f) - mu * mu;
        const float rstd = rsqrtf(var + 1e-5f);

        f32x4 o0, o1;
        o0.x = (v[0] - mu) * rstd * g0.x + be0.x;
        o0.y = (v[1] - mu) * rstd * g0.y + be0.y;
        o0.z = (v[2] - mu) * rstd * g0.z + be0.z;
        o0.w = (v[3] - mu) * rstd * g0.w + be0.w;
        o1.x = (v[4] - mu) * rstd * g1.x + be1.x;
        o1.y = (v[5] - mu) * rstd * g1.y + be1.y;
        o1.z = (v[6] - mu) * rstd * g1.z + be1.z;
        o1.w = (v[7] - mu) * rstd * g1.w + be1.w;

        float* dst = out + (rowBase + lnode) * H + f0;
        *(f32x4*)(dst)     = o0;
        *(f32x4*)(dst + 4) = o1;
    }
}

extern "C" void kernel_launch(void* const* d_in, const int* in_sizes, int n_in,
                              void* d_out, int out_size, void* d_ws, size_t ws_size,
                              hipStream_t stream) {
    const float* x     = (const float*)d_in[0];
    const int*   ei    = (const int*)d_in[1];
    const int*   et    = (const int*)d_in[2];
    const float* emb   = (const float*)d_in[3];
    const float* Wself = (const float*)d_in[4];
    const float* bself = (const float*)d_in[5];
    const float* Wmsg  = (const float*)d_in[6];
    const float* bmsg  = (const float*)d_in[7];
    const float* gamma = (const float*)d_in[8];
    const float* beta  = (const float*)d_in[9];
    float* out = (float*)d_out;

    const int E = in_sizes[2];
    const int N = in_sizes[0] / H;
    const int T = in_sizes[3] / H;
    const int nTiles = N / TM;

    auto rnd = [](size_t b) { return (b + 255) & ~(size_t)255; };
    const size_t sz_xb    = rnd((size_t)N * H * 2);
    const size_t sz_embb  = rnd((size_t)T * H * 2);
    const size_t sz_agg   = rnd((size_t)N * H * 2);
    const size_t sz_bkt16 = rnd((size_t)N * BSTR16 * 4);           // tier A
    const size_t sz_ovf   = rnd((size_t)(8 + 2 * OVFCAP) * 4);     // tier A spill
    const size_t sz_cnt   = rnd((size_t)N * 4);
    const size_t sz_bkt24 = rnd((size_t)N * MAXDEG * 4);           // tier B
    const size_t needA = sz_xb + sz_embb + sz_agg + sz_bkt16 + sz_ovf;
    const size_t needB = sz_agg + sz_cnt + sz_bkt24;

    const bool okT = (T <= 16) && (N <= (1 << 18));
    const bool tierA = okT && (ws_size >= needA) && (N % 32 == 0);
    const bool tierB = okT && (ws_size >= needB) && (N % TM == 0);

    if (tierA) {
        uint8_t* p = (uint8_t*)d_ws;
        unsigned short* xb   = (unsigned short*)p;  p += sz_xb;
        unsigned short* embb = (unsigned short*)p;  p += sz_embb;
        unsigned short* aggb = (unsigned short*)p;  p += sz_agg;
        int* bucket = (int*)p;                      p += sz_bkt16;
        int* ovf    = (int*)p;

        hipMemsetAsync(bucket, 0, sz_bkt16 + sz_ovf, stream);

        const int t8x = N * H / 8, t8e = T * H / 8;
        int prepWork = (t8x + t8e) > E ? (t8x + t8e) : E;
        prep_kernel<<<(prepWork + 255) / 256, 256, 0, stream>>>(
            x, emb, xb, embb, ei, et, bucket, ovf, t8x, t8e, E);

        const int nGroups = N >> 4;
        int aggGrid = nGroups < 6250 ? nGroups : 6250;
        aggregate_bf16_kernel<<<aggGrid, 256, 0, stream>>>(
            xb, embb, bucket, ovf, ei, et, aggb, N, E, T);

        const int nSuper = N / 32;
        int gemmGrid = nSuper < 1024 ? nSuper : 1024;   // 4 blocks/CU, all resident
        gemm_ln32_kernel<<<gemmGrid, 256, 0, stream>>>(
            xb, aggb, Wself, bself, Wmsg, bmsg, gamma, beta, out, nSuper);
    } else if (tierB) {
        uint8_t* p = (uint8_t*)d_ws;
        unsigned short* aggb = (unsigned short*)p;  p += sz_agg;
        int* cnt    = (int*)p;                      p += sz_cnt;
        int* bucket = (int*)p;

        hipMemsetAsync(cnt, 0, (size_t)N * sizeof(int), stream);

        if (E > 0) {
            prep_edges_kernel<<<(E + 255) / 256, 256, 0, stream>>>(
                ei, et, cnt, bucket, E);
        }
        const int nGroups = N >> 4;
        int aggGrid = nGroups < 4096 ? nGroups : 4096;
        aggregate_f32_kernel<<<aggGrid, 256, 0, stream>>>(
            x, emb, cnt, bucket, ei, et, aggb, N, E, T);

        int gemmGrid = nTiles < 2048 ? nTiles : 2048;
        gemm_ln16_kernel<<<gemmGrid, 256, 0, stream>>>(
            x, aggb, Wself, bself, Wmsg, bmsg, gamma, beta, out, nTiles);
    } else {
        hipMemsetAsync(out, 0, (size_t)N * H * sizeof(float), stream);
        const long long sthreads = (long long)E * 32;
        scatter_kernel<<<(int)((sthreads + 255) / 256), 256, 0, stream>>>(
            x, ei, et, emb, out, E);
        int grid = 2500;
        if (grid > nTiles) grid = nTiles;
        gemm_ln_f32_kernel<<<grid, 256, 0, stream>>>(
            x, Wself, bself, Wmsg, bmsg, gamma, beta, out, nTiles);
    }
}

// Round 12
// 287.718 us; speedup vs baseline: 1.1145x; 1.0193x over previous
//
#include <hip/hip_runtime.h>
#include <stdint.h>

#define H 128
#define TM 16
#define MAXDEG 24        // tier B layout
#define BSTR16 16        // tier A bucket row: [count, e0..e14] = 16 ints = one 64B line
#define OVFCAP 4096      // tier A overflow side-array capacity (deg>15 spill)

typedef __attribute__((ext_vector_type(8))) short short8;
typedef __attribute__((ext_vector_type(4))) float f32x4;
typedef __attribute__((ext_vector_type(4))) int i32x4;

__device__ __forceinline__ unsigned short f2bf(float f) {
    union { float f; unsigned u; } v; v.f = f;
    unsigned u = v.u;
    u += 0x7fffu + ((u >> 16) & 1u);   // round-to-nearest-even
    return (unsigned short)(u >> 16);
}

__device__ __forceinline__ float bf2f(unsigned short u) {
    union { unsigned u; float f; } v; v.u = ((unsigned)u) << 16; return v.f;
}

__device__ __forceinline__ short8 cvt8(f32x4 a, f32x4 b) {
    short8 r;
    r[0] = (short)f2bf(a.x); r[1] = (short)f2bf(a.y);
    r[2] = (short)f2bf(a.z); r[3] = (short)f2bf(a.w);
    r[4] = (short)f2bf(b.x); r[5] = (short)f2bf(b.y);
    r[6] = (short)f2bf(b.z); r[7] = (short)f2bf(b.w);
    return r;
}

__device__ __forceinline__ void gadd(int entry, const unsigned short* xb,
                                     const short* emb_s, int l, float* acc) {
    int s = entry & 0x3FFFF, t = entry >> 18;
    short8 xv = *(const short8*)(xb + (size_t)s * H + l * 8);
    short8 ev = *(const short8*)&emb_s[t * 136 + l * 8];
#pragma unroll
    for (int j = 0; j < 8; ++j)
        acc[j] += bf2f((unsigned short)xv[j]) + bf2f((unsigned short)ev[j]);
}

__device__ __forceinline__ void csr_insert(int src, int dst, int t,
                                           int* bucket, int* ovf) {
    int entry = src | (t << 18);
    int* row = bucket + ((size_t)dst << 4);
    int pos = atomicAdd(row, 1);
    if (pos < 15) {
        row[1 + pos] = entry;
    } else {
        int j = atomicAdd(ovf, 1);
        if (j < OVFCAP) { ovf[8 + 2 * j] = dst; ovf[8 + 2 * j + 1] = entry; }
    }
}

// ---------------------------------------------------------------------------
// Tier A prep (R11-proven + weight/bias pre-conversion): one conversion unit
// per thread; edges sliced UNIFORMLY across blocks so each block's ~2 atomic
// chains hide under its 256 conversion threads. NT LOADS only (x/emb read-
// once); REGULAR stores keep xb/embb L2/L3-resident for aggregate (R10
// lesson). NEW: Wself/Wmsg -> bf16 wb and bself+bmsg -> biasc precomputed
// here so gemm's per-block prologue is 16 plain loads (no cvt ALU).
// Bucket row = 16 ints (one 64B line): row[0]=count, row[1+pos]=entry.
// ---------------------------------------------------------------------------
__global__ __launch_bounds__(256) void prep_kernel(
    const float* __restrict__ x, const float* __restrict__ emb,
    const float* __restrict__ Wself, const float* __restrict__ Wmsg,
    const float* __restrict__ bself, const float* __restrict__ bmsg,
    unsigned short* __restrict__ xb, unsigned short* __restrict__ embb,
    unsigned short* __restrict__ wb, float* __restrict__ biasc,
    const int* __restrict__ ei, const int* __restrict__ et,
    int* __restrict__ bucket, int* __restrict__ ovf,
    int total8x, int total8e, int total8w, int E)
{
    const int tid = threadIdx.x;
    const int i = blockIdx.x * 256 + tid;

    // ---- this block's edge slice (uniform across grid) ----
    const int nb = gridDim.x;
    const int e0 = (int)(((long long)blockIdx.x * E) / nb);
    const int e1 = (int)(((long long)(blockIdx.x + 1) * E) / nb);

    // ---- issue first-round edge loads early (overlap with conversion) ----
    int src = 0, dst = 0, t = 0;
    int e = e0 + tid;
    const bool hasE = (e < e1);
    if (hasE) {
        src = ei[e];
        dst = ei[E + e];
        t   = et[e];
    }

    // ---- bias precompute (block 0 only; also does its x units below) ----
    if (blockIdx.x == 0 && tid < H) biasc[tid] = bself[tid] + bmsg[tid];

    // ---- streaming conversion (NT loads; regular stores -> L3-resident) ----
    if (i < total8x) {
        f32x4 a = __builtin_nontemporal_load(((const f32x4*)x) + 2 * i);
        f32x4 b = __builtin_nontemporal_load(((const f32x4*)x) + 2 * i + 1);
        ((short8*)xb)[i] = cvt8(a, b);
    } else if (i < total8x + total8e) {
        int j = i - total8x;
        f32x4 a = __builtin_nontemporal_load(((const f32x4*)emb) + 2 * j);
        f32x4 b = __builtin_nontemporal_load(((const f32x4*)emb) + 2 * j + 1);
        ((short8*)embb)[j] = cvt8(a, b);
    } else if (i < total8x + total8e + total8w) {
        int j = i - total8x - total8e;
        const int half = total8w >> 1;
        const float* srcW = (j < half) ? (Wself + (size_t)j * 8)
                                       : (Wmsg + (size_t)(j - half) * 8);
        f32x4 a = *(const f32x4*)srcW;
        f32x4 b = *(const f32x4*)(srcW + 4);
        ((short8*)wb)[j] = cvt8(a, b);
    }

    // ---- CSR insert (atomic latency hidden under the conversion above) ----
    if (hasE) csr_insert(src, dst, t, bucket, ovf);

    // rare tail: slice larger than one thread-round (not at default shapes)
    for (e = e0 + 256 + tid; e < e1; e += 256) {
        csr_insert(ei[e], ei[E + e], et[e], bucket, ovf);
    }
}

// Tier B prep: CSR only (old separate cnt/bucket layout).
__global__ __launch_bounds__(256) void prep_edges_kernel(
    const int* __restrict__ ei, const int* __restrict__ et,
    int* __restrict__ cnt, int* __restrict__ bucket, int E)
{
    int e = blockIdx.x * 256 + threadIdx.x;
    if (e >= E) return;
    int src = ei[e];
    int dst = ei[E + e];
    int t   = et[e];
    int pos = atomicAdd(&cnt[dst], 1);
    if (pos < MAXDEG) bucket[(size_t)dst * MAXDEG + pos] = src | (t << 18);
}

// ---------------------------------------------------------------------------
// Tier A aggregate: bf16 gather, fp32 accumulate, bf16 write. (R6-R11 proven)
// One 16-lane group per node. Header quad = count + entries 0..2.
// deg>15: 15 inline entries + ovf scan. Spill-overflow: full E-scan.
// Grid 2048 = 8 blocks/CU (wave cap), all resident.
// ---------------------------------------------------------------------------
__global__ __launch_bounds__(256) void aggregate_bf16_kernel(
    const unsigned short* __restrict__ xb, const unsigned short* __restrict__ embb,
    const int* __restrict__ bucket, const int* __restrict__ ovf,
    const int* __restrict__ ei, const int* __restrict__ et,
    unsigned short* __restrict__ aggb, int N, int E, int T)
{
    __shared__ __align__(16) short emb_s[16 * 136];   // padded stride 136

    const int tid = threadIdx.x;
    const int l   = tid & 15;      // feature chunk: l*8 .. l*8+7
    if (tid < T * 16) {
        int t = tid >> 4;
        *(short8*)&emb_s[t * 136 + l * 8] = *(const short8*)(embb + t * H + l * 8);
    }
    __syncthreads();

    const int nGroups = N >> 4;
    for (int g = blockIdx.x; g < nGroups; g += gridDim.x) {
        const int node = (g << 4) + (tid >> 4);

        const int* row = bucket + ((size_t)node << 4);
        i32x4 q = *(const i32x4*)row;   // count + entries 0,1,2
        const int c = q.x;

        float acc[8] = {0.f, 0.f, 0.f, 0.f, 0.f, 0.f, 0.f, 0.f};

        bool fullscan = false;
        int cc = c, nov = 0;
        if (c > 15) {
            nov = ovf[0];
            if (nov > OVFCAP) fullscan = true;   // spill overflowed: rescan
            cc = 15;
        }

        if (!fullscan) {
            {
                const bool b0 = cc > 0, b1 = cc > 1, b2 = cc > 2;
                short8 xv0, xv1, xv2, ev0, ev1, ev2;
                if (b0) {
                    int s = q.y & 0x3FFFF, t = q.y >> 18;
                    xv0 = *(const short8*)(xb + (size_t)s * H + l * 8);
                    ev0 = *(const short8*)&emb_s[t * 136 + l * 8];
                }
                if (b1) {
                    int s = q.z & 0x3FFFF, t = q.z >> 18;
                    xv1 = *(const short8*)(xb + (size_t)s * H + l * 8);
                    ev1 = *(const short8*)&emb_s[t * 136 + l * 8];
                }
                if (b2) {
                    int s = q.w & 0x3FFFF, t = q.w >> 18;
                    xv2 = *(const short8*)(xb + (size_t)s * H + l * 8);
                    ev2 = *(const short8*)&emb_s[t * 136 + l * 8];
                }
                if (b0) {
#pragma unroll
                    for (int j = 0; j < 8; ++j) acc[j] += bf2f((unsigned short)xv0[j]) + bf2f((unsigned short)ev0[j]);
                }
                if (b1) {
#pragma unroll
                    for (int j = 0; j < 8; ++j) acc[j] += bf2f((unsigned short)xv1[j]) + bf2f((unsigned short)ev1[j]);
                }
                if (b2) {
#pragma unroll
                    for (int j = 0; j < 8; ++j) acc[j] += bf2f((unsigned short)xv2[j]) + bf2f((unsigned short)ev2[j]);
                }
            }
            for (int i0 = 3; i0 < cc; i0 += 4) {
                i32x4 p = *(const i32x4*)(row + 1 + i0);   // entries i0..i0+3
                const int rem = cc - i0;
                const bool h1 = rem > 1, h2 = rem > 2, h3 = rem > 3;
                short8 xv0, xv1, xv2, xv3, ev0, ev1, ev2, ev3;
                {
                    int s = p.x & 0x3FFFF, t = p.x >> 18;
                    xv0 = *(const short8*)(xb + (size_t)s * H + l * 8);
                    ev0 = *(const short8*)&emb_s[t * 136 + l * 8];
                }
                if (h1) {
                    int s = p.y & 0x3FFFF, t = p.y >> 18;
                    xv1 = *(const short8*)(xb + (size_t)s * H + l * 8);
                    ev1 = *(const short8*)&emb_s[t * 136 + l * 8];
                }
                if (h2) {
                    int s = p.z & 0x3FFFF, t = p.z >> 18;
                    xv2 = *(const short8*)(xb + (size_t)s * H + l * 8);
                    ev2 = *(const short8*)&emb_s[t * 136 + l * 8];
                }
                if (h3) {
                    int s = p.w & 0x3FFFF, t = p.w >> 18;
                    xv3 = *(const short8*)(xb + (size_t)s * H + l * 8);
                    ev3 = *(const short8*)&emb_s[t * 136 + l * 8];
                }
#pragma unroll
                for (int j = 0; j < 8; ++j) acc[j] += bf2f((unsigned short)xv0[j]) + bf2f((unsigned short)ev0[j]);
                if (h1) {
#pragma unroll
                    for (int j = 0; j < 8; ++j) acc[j] += bf2f((unsigned short)xv1[j]) + bf2f((unsigned short)ev1[j]);
                }
                if (h2) {
#pragma unroll
                    for (int j = 0; j < 8; ++j) acc[j] += bf2f((unsigned short)xv2[j]) + bf2f((unsigned short)ev2[j]);
                }
                if (h3) {
#pragma unroll
                    for (int j = 0; j < 8; ++j) acc[j] += bf2f((unsigned short)xv3[j]) + bf2f((unsigned short)ev3[j]);
                }
            }
            if (c > 15) {
                for (int j = 0; j < nov; ++j) {
                    if (ovf[8 + 2 * j] == node) gadd(ovf[8 + 2 * j + 1], xb, emb_s, l, acc);
                }
            }
        } else {
            for (int e = 0; e < E; ++e) {
                if (ei[E + e] == node) gadd(ei[e] | (et[e] << 18), xb, emb_s, l, acc);
            }
        }

        short8 r;
#pragma unroll
        for (int j = 0; j < 8; ++j) r[j] = (short)f2bf(acc[j]);
        *(short8*)(aggb + (size_t)node * H + l * 8) = r;
    }
}

// ---------------------------------------------------------------------------
// Tier A GEMM+LN: R5 structure (2 barriers, separate a/o buffers). Grid 1024
// = 4 blocks/CU (LDS cap), all resident. Weight fragments loaded directly
// from pre-converted bf16 wb (prep) -> prologue is 16 plain 16B loads.
// LN: line-complete NT stores. (R8/R11-proven)
// ---------------------------------------------------------------------------
__global__ __launch_bounds__(256) void gemm_ln32_kernel(
    const unsigned short* __restrict__ xb, const unsigned short* __restrict__ aggb,
    const unsigned short* __restrict__ wb, const float* __restrict__ biasc,
    const float* __restrict__ gamma, const float* __restrict__ beta,
    float* __restrict__ out, int nSuper)
{
    __shared__ __align__(16) short a_stage[32 * 264];  // 32 x (256+8 pad) bf16
    __shared__ __align__(16) float o_stage[32 * 132];  // 32 x (128+4 pad) f32

    const int tid  = threadIdx.x;
    const int wave = tid >> 6;
    const int lane = tid & 63;
    const int col  = lane & 15;
    const int quad = lane >> 4;

    // ---- B fragments (pre-converted bf16) into registers; once per block ----
    short8 bfrag[2][8];
    float bias[2];
#pragma unroll
    for (int s = 0; s < 2; ++s) {
        const int h = (wave * 2 + s) * 16 + col;
        bias[s] = biasc[h];
#pragma unroll
        for (int kst = 0; kst < 8; ++kst) {
            const unsigned short* wp = wb + ((kst < 4) ? 0 : (H * H))
                                     + (size_t)h * H + (kst & 3) * 32 + quad * 8;
            bfrag[s][kst] = *(const short8*)wp;
        }
    }

    // LN mapping: 16 lanes/row; lane l owns feats [l4,+4) and [64+l4,+4)
    const int lrow = tid >> 4;           // 0..15 (row within 16-row half)
    const int l4 = (tid & 15) * 4;
    f32x4 g0  = *(const f32x4*)(gamma + l4);
    f32x4 g1  = *(const f32x4*)(gamma + 64 + l4);
    f32x4 be0 = *(const f32x4*)(beta + l4);
    f32x4 be1 = *(const f32x4*)(beta + 64 + l4);

    const int srow = tid >> 3;   // 0..31: staging row
    const int sq   = tid & 7;    // 0..7

    for (int st = blockIdx.x; st < nSuper; st += gridDim.x) {
        const size_t rowBase = (size_t)st * 32;

        // ---- stage 32x256 bf16: sq<4 -> xb chunks, sq>=4 -> aggb chunks ----
        {
            const unsigned short* src = (sq < 4)
                ? (xb   + (rowBase + srow) * H + sq * 32)
                : (aggb + (rowBase + srow) * H + (sq - 4) * 32);
            short* dstl = &a_stage[srow * 264 + (sq & 3) * 32 + ((sq >> 2) << 7)];
            *(short8*)(dstl)      = ((const short8*)src)[0];
            *(short8*)(dstl + 8)  = ((const short8*)src)[1];
            *(short8*)(dstl + 16) = ((const short8*)src)[2];
            *(short8*)(dstl + 24) = ((const short8*)src)[3];
        }
        __syncthreads();   // sync#1: a_stage visible

        // ---- MFMA: 2 row-tiles x 2 feature-halves, K=256 ----
        f32x4 acc00 = {0.f,0.f,0.f,0.f}, acc01 = {0.f,0.f,0.f,0.f};
        f32x4 acc10 = {0.f,0.f,0.f,0.f}, acc11 = {0.f,0.f,0.f,0.f};
        {
            short8 afr[8];
#pragma unroll
            for (int kst = 0; kst < 8; ++kst)
                afr[kst] = *(const short8*)&a_stage[col * 264 + kst * 32 + quad * 8];
#pragma unroll
            for (int kst = 0; kst < 8; ++kst) {
                acc00 = __builtin_amdgcn_mfma_f32_16x16x32_bf16(afr[kst], bfrag[0][kst], acc00, 0, 0, 0);
                acc01 = __builtin_amdgcn_mfma_f32_16x16x32_bf16(afr[kst], bfrag[1][kst], acc01, 0, 0, 0);
            }
#pragma unroll
            for (int kst = 0; kst < 8; ++kst)
                afr[kst] = *(const short8*)&a_stage[(16 + col) * 264 + kst * 32 + quad * 8];
#pragma unroll
            for (int kst = 0; kst < 8; ++kst) {
                acc10 = __builtin_amdgcn_mfma_f32_16x16x32_bf16(afr[kst], bfrag[0][kst], acc10, 0, 0, 0);
                acc11 = __builtin_amdgcn_mfma_f32_16x16x32_bf16(afr[kst], bfrag[1][kst], acc11, 0, 0, 0);
            }
        }

        // ---- bias + relu -> o_stage ----
        {
            const int h0 = (wave * 2) * 16 + col;
            const int h1 = h0 + 16;
#pragma unroll
            for (int r = 0; r < 4; ++r) {
                const int m = quad * 4 + r;
                float v;
                v = acc00[r] + bias[0]; o_stage[m * 132 + h0]        = v > 0.f ? v : 0.f;
                v = acc01[r] + bias[1]; o_stage[m * 132 + h1]        = v > 0.f ? v : 0.f;
                v = acc10[r] + bias[0]; o_stage[(16 + m) * 132 + h0] = v > 0.f ? v : 0.f;
                v = acc11[r] + bias[1]; o_stage[(16 + m) * 132 + h1] = v > 0.f ? v : 0.f;
            }
        }
        __syncthreads();   // sync#2: o_stage visible; all a_stage reads retired

        // ---- LayerNorm: two 16-row passes; line-complete NT stores ----
#pragma unroll
        for (int half = 0; half < 2; ++half) {
            const int row = half * 16 + lrow;
            const float* orow = &o_stage[row * 132];
            f32x4 va = *(const f32x4*)(orow + l4);        // feats l4..l4+3
            f32x4 vb = *(const f32x4*)(orow + 64 + l4);   // feats 64+l4..

            float s1 = (va.x + va.y + va.z + va.w) + (vb.x + vb.y + vb.z + vb.w);
            float s2 = va.x*va.x + va.y*va.y + va.z*va.z + va.w*va.w
                     + vb.x*vb.x + vb.y*vb.y + vb.z*vb.z + vb.w*vb.w;
#pragma unroll
            for (int m = 1; m < 16; m <<= 1) {
                s1 += __shfl_xor(s1, m, 64);
                s2 += __shfl_xor(s2, m, 64);
            }
            const float mu = s1 * (1.f / 128.f);
            const float var = s2 * (1.f / 128.f) - mu * mu;
            const float rstd = rsqrtf(var + 1e-5f);

            f32x4 o0, o1;
            o0.x = (va.x - mu) * rstd * g0.x + be0.x;
            o0.y = (va.y - mu) * rstd * g0.y + be0.y;
            o0.z = (va.z - mu) * rstd * g0.z + be0.z;
            o0.w = (va.w - mu) * rstd * g0.w + be0.w;
            o1.x = (vb.x - mu) * rstd * g1.x + be1.x;
            o1.y = (vb.y - mu) * rstd * g1.y + be1.y;
            o1.z = (vb.z - mu) * rstd * g1.z + be1.z;
            o1.w = (vb.w - mu) * rstd * g1.w + be1.w;

            float* dst = out + (rowBase + row) * H;
            __builtin_nontemporal_store(o0, (f32x4*)(dst + l4));
            __builtin_nontemporal_store(o1, (f32x4*)(dst + 64 + l4));
        }
        // no trailing barrier: next-iter a_stage writes happen only after
        // every wave passed sync#2.
    }
}

// ---------------------------------------------------------------------------
// Tier B (round-1 proven): fp32 gather aggregate + 16-row gemm reading fp32 x.
// ---------------------------------------------------------------------------
__global__ __launch_bounds__(256) void aggregate_f32_kernel(
    const float* __restrict__ x, const float* __restrict__ emb,
    const int* __restrict__ cnt, const int* __restrict__ bucket,
    const int* __restrict__ ei, const int* __restrict__ et,
    unsigned short* __restrict__ aggb, int N, int E, int T)
{
    __shared__ __align__(16) float emb_s[16 * 132];

    const int tid = threadIdx.x;
    for (int i = tid; i < T * H; i += 256)
        emb_s[(i >> 7) * 132 + (i & 127)] = emb[i];
    __syncthreads();

    const int l = tid & 15;
    const int nGroups = N >> 4;

    for (int g = blockIdx.x; g < nGroups; g += gridDim.x) {
        const int node = (g << 4) + (tid >> 4);
        const int* b = bucket + (size_t)node * MAXDEG;
        i32x4 p = *(const i32x4*)b;
        const int c = cnt[node];

        f32x4 acc0 = {0.f,0.f,0.f,0.f};
        f32x4 acc1 = {0.f,0.f,0.f,0.f};

        if (c <= MAXDEG) {
            for (int i0 = 0; i0 < c; i0 += 4) {
                if (i0 > 0) p = *(const i32x4*)(b + i0);
                const int rem = c - i0;
                const bool h1 = rem > 1, h2 = rem > 2, h3 = rem > 3;
                f32x4 x00,x01,e00,e01,x10,x11,e10,e11,x20,x21,e20,e21,x30,x31,e30,e31;
                {
                    int s = p.x & 0x3FFFF, t = p.x >> 18;
                    const float* xp = x + (size_t)s * H + l * 8;
                    const float* ep = emb_s + t * 132 + l * 8;
                    x00 = *(const f32x4*)xp; x01 = *(const f32x4*)(xp + 4);
                    e00 = *(const f32x4*)ep; e01 = *(const f32x4*)(ep + 4);
                }
                if (h1) {
                    int s = p.y & 0x3FFFF, t = p.y >> 18;
                    const float* xp = x + (size_t)s * H + l * 8;
                    const float* ep = emb_s + t * 132 + l * 8;
                    x10 = *(const f32x4*)xp; x11 = *(const f32x4*)(xp + 4);
                    e10 = *(const f32x4*)ep; e11 = *(const f32x4*)(ep + 4);
                }
                if (h2) {
                    int s = p.z & 0x3FFFF, t = p.z >> 18;
                    const float* xp = x + (size_t)s * H + l * 8;
                    const float* ep = emb_s + t * 132 + l * 8;
                    x20 = *(const f32x4*)xp; x21 = *(const f32x4*)(xp + 4);
                    e20 = *(const f32x4*)ep; e21 = *(const f32x4*)(ep + 4);
                }
                if (h3) {
                    int s = p.w & 0x3FFFF, t = p.w >> 18;
                    const float* xp = x + (size_t)s * H + l * 8;
                    const float* ep = emb_s + t * 132 + l * 8;
                    x30 = *(const f32x4*)xp; x31 = *(const f32x4*)(xp + 4);
                    e30 = *(const f32x4*)ep; e31 = *(const f32x4*)(ep + 4);
                }
                acc0 += x00 + e00;  acc1 += x01 + e01;
                if (h1) { acc0 += x10 + e10;  acc1 += x11 + e11; }
                if (h2) { acc0 += x20 + e20;  acc1 += x21 + e21; }
                if (h3) { acc0 += x30 + e30;  acc1 += x31 + e31; }
            }
        } else {
            for (int e = 0; e < E; ++e) {
                if (ei[E + e] == node) {
                    int s = ei[e], t = et[e];
                    const float* xp = x + (size_t)s * H + l * 8;
                    const float* ep = emb_s + t * 132 + l * 8;
                    f32x4 a0 = *(const f32x4*)xp, a1 = *(const f32x4*)(xp + 4);
                    f32x4 b0 = *(const f32x4*)ep, b1 = *(const f32x4*)(ep + 4);
                    acc0 += a0 + b0;  acc1 += a1 + b1;
                }
            }
        }
        *(short8*)(aggb + (size_t)node * H + l * 8) = cvt8(acc0, acc1);
    }
}

__global__ __launch_bounds__(256) void gemm_ln16_kernel(
    const float* __restrict__ x, const unsigned short* __restrict__ aggb,
    const float* __restrict__ Wself, const float* __restrict__ bself,
    const float* __restrict__ Wmsg, const float* __restrict__ bmsg,
    const float* __restrict__ gamma, const float* __restrict__ beta,
    float* __restrict__ out, int nTiles)
{
    __shared__ __align__(16) short a_stage[TM * 264];
    __shared__ __align__(16) float o_stage[TM * 132];

    const int tid  = threadIdx.x;
    const int wave = tid >> 6;
    const int lane = tid & 63;
    const int col  = lane & 15;
    const int quad = lane >> 4;

    short8 bfrag[2][8];
    float bias[2];
#pragma unroll
    for (int s = 0; s < 2; ++s) {
        const int h = (wave * 2 + s) * 16 + col;
        bias[s] = bself[h] + bmsg[h];
#pragma unroll
        for (int kst = 0; kst < 8; ++kst) {
            const float* W = (kst < 4) ? Wself : Wmsg;
            const int k0 = (kst & 3) * 32 + quad * 8;
            const float* p = W + (size_t)h * H + k0;
            bfrag[s][kst] = cvt8(*(const f32x4*)p, *(const f32x4*)(p + 4));
        }
    }

    const int lnode = tid >> 4;
    const int f0 = (tid & 15) * 8;
    f32x4 g0  = *(const f32x4*)(gamma + f0);
    f32x4 g1  = *(const f32x4*)(gamma + f0 + 4);
    f32x4 be0 = *(const f32x4*)(beta + f0);
    f32x4 be1 = *(const f32x4*)(beta + f0 + 4);

    const int node = tid >> 4;
    const int seg  = tid & 15;

    for (int tile = blockIdx.x; tile < nTiles; tile += gridDim.x) {
        const size_t rowBase = (size_t)tile * TM;
        if (seg < 8) {
            const float* src = x + (rowBase + node) * H + seg * 16;
            f32x4 v0 = ((const f32x4*)src)[0];
            f32x4 v1 = ((const f32x4*)src)[1];
            f32x4 v2 = ((const f32x4*)src)[2];
            f32x4 v3 = ((const f32x4*)src)[3];
            *(short8*)&a_stage[node * 264 + seg * 16]     = cvt8(v0, v1);
            *(short8*)&a_stage[node * 264 + seg * 16 + 8] = cvt8(v2, v3);
        } else {
            const unsigned short* src = aggb + (rowBase + node) * H + (seg - 8) * 16;
            *(short8*)&a_stage[node * 264 + 128 + (seg - 8) * 16]     = *(const short8*)src;
            *(short8*)&a_stage[node * 264 + 128 + (seg - 8) * 16 + 8] = *(const short8*)(src + 8);
        }
        __syncthreads();

        short8 afr[8];
#pragma unroll
        for (int kst = 0; kst < 8; ++kst)
            afr[kst] = *(const short8*)(&a_stage[col * 264 + kst * 32 + quad * 8]);

        f32x4 acc0 = {0.f,0.f,0.f,0.f};
        f32x4 acc1 = {0.f,0.f,0.f,0.f};
#pragma unroll
        for (int kst = 0; kst < 8; ++kst) {
            acc0 = __builtin_amdgcn_mfma_f32_16x16x32_bf16(afr[kst], bfrag[0][kst], acc0, 0, 0, 0);
            acc1 = __builtin_amdgcn_mfma_f32_16x16x32_bf16(afr[kst], bfrag[1][kst], acc1, 0, 0, 0);
        }

#pragma unroll
        for (int s = 0; s < 2; ++s) {
            const int h = (wave * 2 + s) * 16 + col;
            f32x4 a = s ? acc1 : acc0;
#pragma unroll
            for (int r = 0; r < 4; ++r) {
                const int m = quad * 4 + r;
                float v = a[r] + bias[s];
                o_stage[m * 132 + h] = v > 0.f ? v : 0.f;
            }
        }
        __syncthreads();

        float v[8];
        float s1 = 0.f, s2 = 0.f;
#pragma unroll
        for (int j = 0; j < 8; ++j) {
            v[j] = o_stage[lnode * 132 + f0 + j];
            s1 += v[j];
            s2 += v[j] * v[j];
        }
#pragma unroll
        for (int m = 1; m < 16; m <<= 1) {
            s1 += __shfl_xor(s1, m, 64);
            s2 += __shfl_xor(s2, m, 64);
        }
        const float mu = s1 * (1.f / 128.f);
        const float var = s2 * (1.f / 128.f) - mu * mu;
        const float rstd = rsqrtf(var + 1e-5f);

        f32x4 o0, o1;
        o0.x = (v[0] - mu) * rstd * g0.x + be0.x;
        o0.y = (v[1] - mu) * rstd * g0.y + be0.y;
        o0.z = (v[2] - mu) * rstd * g0.z + be0.z;
        o0.w = (v[3] - mu) * rstd * g0.w + be0.w;
        o1.x = (v[4] - mu) * rstd * g1.x + be1.x;
        o1.y = (v[5] - mu) * rstd * g1.y + be1.y;
        o1.z = (v[6] - mu) * rstd * g1.z + be1.z;
        o1.w = (v[7] - mu) * rstd * g1.w + be1.w;

        float* dst = out + (rowBase + lnode) * H + f0;
        __builtin_nontemporal_store(o0, (f32x4*)dst);
        __builtin_nontemporal_store(o1, (f32x4*)(dst + 4));
    }
}

// ---------------------------------------------------------------------------
// Tier-C fallback: atomic scatter + fp32 gemm (agg staged in d_out).
// ---------------------------------------------------------------------------
__global__ __launch_bounds__(256) void scatter_kernel(
    const float* __restrict__ x, const int* __restrict__ ei,
    const int* __restrict__ et, const float* __restrict__ emb,
    float* __restrict__ agg, int E)
{
    int g = blockIdx.x * 256 + threadIdx.x;
    int e = g >> 5;
    int l = g & 31;
    if (e >= E) return;
    int src = ei[e];
    int dst = ei[E + e];
    int t   = et[e];
    f32x4 xv = *(const f32x4*)(x   + (size_t)src * H + l * 4);
    f32x4 ev = *(const f32x4*)(emb + (size_t)t   * H + l * 4);
    float* b = agg + (size_t)dst * H + l * 4;
    atomicAdd(b + 0, xv.x + ev.x);
    atomicAdd(b + 1, xv.y + ev.y);
    atomicAdd(b + 2, xv.z + ev.z);
    atomicAdd(b + 3, xv.w + ev.w);
}

__global__ __launch_bounds__(256) void gemm_ln_f32_kernel(
    const float* __restrict__ x,
    const float* __restrict__ Wself, const float* __restrict__ bself,
    const float* __restrict__ Wmsg, const float* __restrict__ bmsg,
    const float* __restrict__ gamma, const float* __restrict__ beta,
    float* __restrict__ out, int nTiles)
{
    __shared__ __align__(16) short a_stage[TM * 264];
    __shared__ __align__(16) float o_stage[TM * 132];

    const int tid  = threadIdx.x;
    const int wave = tid >> 6;
    const int lane = tid & 63;
    const int col  = lane & 15;
    const int quad = lane >> 4;

    short8 bfrag[2][8];
    float bias[2];
#pragma unroll
    for (int s = 0; s < 2; ++s) {
        const int h = (wave * 2 + s) * 16 + col;
        bias[s] = bself[h] + bmsg[h];
#pragma unroll
        for (int kst = 0; kst < 8; ++kst) {
            const float* W = (kst < 4) ? Wself : Wmsg;
            const int k0 = (kst & 3) * 32 + quad * 8;
            const float* p = W + (size_t)h * H + k0;
            bfrag[s][kst] = cvt8(*(const f32x4*)p, *(const f32x4*)(p + 4));
        }
    }

    const int lnode = tid >> 4;
    const int f0 = (tid & 15) * 8;
    f32x4 g0  = *(const f32x4*)(gamma + f0);
    f32x4 g1  = *(const f32x4*)(gamma + f0 + 4);
    f32x4 be0 = *(const f32x4*)(beta + f0);
    f32x4 be1 = *(const f32x4*)(beta + f0 + 4);

    for (int tile = blockIdx.x; tile < nTiles; tile += gridDim.x) {
        const size_t rowBase = (size_t)tile * TM;
        {
            const int node = tid >> 4;
            const int seg  = tid & 15;
            const int k0   = seg * 16;
            const float* src = (seg < 8)
                ? (x   + (rowBase + node) * H + k0)
                : (out + (rowBase + node) * H + (k0 - 128));
            f32x4 v0 = ((const f32x4*)src)[0];
            f32x4 v1 = ((const f32x4*)src)[1];
            f32x4 v2 = ((const f32x4*)src)[2];
            f32x4 v3 = ((const f32x4*)src)[3];
            *(short8*)(&a_stage[node * 264 + k0])     = cvt8(v0, v1);
            *(short8*)(&a_stage[node * 264 + k0 + 8]) = cvt8(v2, v3);
        }
        __syncthreads();

        short8 afr[8];
#pragma unroll
        for (int kst = 0; kst < 8; ++kst)
            afr[kst] = *(const short8*)(&a_stage[col * 264 + kst * 32 + quad * 8]);

        f32x4 acc0 = {0.f,0.f,0.f,0.f};
        f32x4 acc1 = {0.f,0.f,0.f,0.f};
#pragma unroll
        for (int kst = 0; kst < 8; ++kst) {
            acc0 = __builtin_amdgcn_mfma_f32_16x16x32_bf16(afr[kst], bfrag[0][kst], acc0, 0, 0, 0);
            acc1 = __builtin_amdgcn_mfma_f32_16x16x32_bf16(afr[kst], bfrag[1][kst], acc1, 0, 0, 0);
        }

#pragma unroll
        for (int s = 0; s < 2; ++s) {
            const int h = (wave * 2 + s) * 16 + col;
            f32x4 a = s ? acc1 : acc0;
#pragma unroll
            for (int r = 0; r < 4; ++r) {
                const int m = quad * 4 + r;
                float v = a[r] + bias[s];
                o_stage[m * 132 + h] = v > 0.f ? v : 0.f;
            }
        }
        __syncthreads();

        float v[8];
        float s1 = 0.f, s2 = 0.f;
#pragma unroll
        for (int j = 0; j < 8; ++j) {
            v[j] = o_stage[lnode * 132 + f0 + j];
            s1 += v[j];
            s2 += v[j] * v[j];
        }
#pragma unroll
        for (int m = 1; m < 16; m <<= 1) {
            s1 += __shfl_xor(s1, m, 64);
            s2 += __shfl_xor(s2, m, 64);
        }
        const float mu = s1 * (1.f / 128.f);
        const float var = s2 * (1.f / 128.f) - mu * mu;
        const float rstd = rsqrtf(var + 1e-5f);

        f32x4 o0, o1;
        o0.x = (v[0] - mu) * rstd * g0.x + be0.x;
        o0.y = (v[1] - mu) * rstd * g0.y + be0.y;
        o0.z = (v[2] - mu) * rstd * g0.z + be0.z;
        o0.w = (v[3] - mu) * rstd * g0.w + be0.w;
        o1.x = (v[4] - mu) * rstd * g1.x + be1.x;
        o1.y = (v[5] - mu) * rstd * g1.y + be1.y;
        o1.z = (v[6] - mu) * rstd * g1.z + be1.z;
        o1.w = (v[7] - mu) * rstd * g1.w + be1.w;

        float* dst = out + (rowBase + lnode) * H + f0;
        *(f32x4*)(dst)     = o0;
        *(f32x4*)(dst + 4) = o1;
    }
}

extern "C" void kernel_launch(void* const* d_in, const int* in_sizes, int n_in,
                              void* d_out, int out_size, void* d_ws, size_t ws_size,
                              hipStream_t stream) {
    const float* x     = (const float*)d_in[0];
    const int*   ei    = (const int*)d_in[1];
    const int*   et    = (const int*)d_in[2];
    const float* emb   = (const float*)d_in[3];
    const float* Wself = (const float*)d_in[4];
    const float* bself = (const float*)d_in[5];
    const float* Wmsg  = (const float*)d_in[6];
    const float* bmsg  = (const float*)d_in[7];
    const float* gamma = (const float*)d_in[8];
    const float* beta  = (const float*)d_in[9];
    float* out = (float*)d_out;

    const int E = in_sizes[2];
    const int N = in_sizes[0] / H;
    const int T = in_sizes[3] / H;
    const int nTiles = N / TM;

    auto rnd = [](size_t b) { return (b + 255) & ~(size_t)255; };
    const size_t sz_xb    = rnd((size_t)N * H * 2);
    const size_t sz_embb  = rnd((size_t)T * H * 2);
    const size_t sz_agg   = rnd((size_t)N * H * 2);
    const size_t sz_wb    = rnd((size_t)2 * H * H * 2);            // bf16 weights
    const size_t sz_bias  = rnd((size_t)H * 4);                    // bself+bmsg
    const size_t sz_bkt16 = rnd((size_t)N * BSTR16 * 4);           // tier A
    const size_t sz_ovf   = rnd((size_t)(8 + 2 * OVFCAP) * 4);     // tier A spill
    const size_t sz_cnt   = rnd((size_t)N * 4);
    const size_t sz_bkt24 = rnd((size_t)N * MAXDEG * 4);           // tier B
    const size_t needA = sz_xb + sz_embb + sz_agg + sz_wb + sz_bias + sz_bkt16 + sz_ovf;
    const size_t needB = sz_agg + sz_cnt + sz_bkt24;

    const bool okT = (T <= 16) && (N <= (1 << 18));
    const bool tierA = okT && (ws_size >= needA) && (N % 32 == 0);
    const bool tierB = okT && (ws_size >= needB) && (N % TM == 0);

    if (tierA) {
        uint8_t* p = (uint8_t*)d_ws;
        unsigned short* xb   = (unsigned short*)p;  p += sz_xb;
        unsigned short* embb = (unsigned short*)p;  p += sz_embb;
        unsigned short* aggb = (unsigned short*)p;  p += sz_agg;
        unsigned short* wb   = (unsigned short*)p;  p += sz_wb;
        float*          biasc= (float*)p;           p += sz_bias;
        int* bucket = (int*)p;                      p += sz_bkt16;
        int* ovf    = (int*)p;

        hipMemsetAsync(bucket, 0, sz_bkt16 + sz_ovf, stream);

        const int t8x = N * H / 8, t8e = T * H / 8, t8w = 2 * H * H / 8;
        int convWork = t8x + t8e + t8w;
        int prepWork = convWork > E ? convWork : E;
        prep_kernel<<<(prepWork + 255) / 256, 256, 0, stream>>>(
            x, emb, Wself, Wmsg, bself, bmsg, xb, embb, wb, biasc,
            ei, et, bucket, ovf, t8x, t8e, t8w, E);

        const int nGroups = N >> 4;
        int aggGrid = nGroups < 2048 ? nGroups : 2048;   // 8 blocks/CU, resident
        aggregate_bf16_kernel<<<aggGrid, 256, 0, stream>>>(
            xb, embb, bucket, ovf, ei, et, aggb, N, E, T);

        const int nSuper = N / 32;
        int gemmGrid = nSuper < 1024 ? nSuper : 1024;    // 4 blocks/CU, resident
        gemm_ln32_kernel<<<gemmGrid, 256, 0, stream>>>(
            xb, aggb, wb, biasc, gamma, beta, out, nSuper);
    } else if (tierB) {
        uint8_t* p = (uint8_t*)d_ws;
        unsigned short* aggb = (unsigned short*)p;  p += sz_agg;
        int* cnt    = (int*)p;                      p += sz_cnt;
        int* bucket = (int*)p;

        hipMemsetAsync(cnt, 0, (size_t)N * sizeof(int), stream);

        if (E > 0) {
            prep_edges_kernel<<<(E + 255) / 256, 256, 0, stream>>>(
                ei, et, cnt, bucket, E);
        }
        const int nGroups = N >> 4;
        int aggGrid = nGroups < 4096 ? nGroups : 4096;
        aggregate_f32_kernel<<<aggGrid, 256, 0, stream>>>(
            x, emb, cnt, bucket, ei, et, aggb, N, E, T);

        int gemmGrid = nTiles < 2048 ? nTiles : 2048;
        gemm_ln16_kernel<<<gemmGrid, 256, 0, stream>>>(
            x, aggb, Wself, bself, Wmsg, bmsg, gamma, beta, out, nTiles);
    } else {
        hipMemsetAsync(out, 0, (size_t)N * H * sizeof(float), stream);
        const long long sthreads = (long long)E * 32;
        scatter_kernel<<<(int)((sthreads + 255) / 256), 256, 0, stream>>>(
            x, ei, et, emb, out, E);
        int grid = 2500;
        if (grid > nTiles) grid = nTiles;
        gemm_ln_f32_kernel<<<grid, 256, 0, stream>>>(
            x, Wself, bself, Wmsg, bmsg, gamma, beta, out, nTiles);
    }
}